// Round 11
// baseline (922.275 us; speedup 1.0000x reference)
//
#include <hip/hip_runtime.h>
#include <hip/hip_bf16.h>
#include <cstdint>

#define L_SEQ 1024
#define BSZ   16
#define DIN   2048
#define DD    2048
#define MROWS (L_SEQ * BSZ)   // 16384
#define NCOLS (3 * DD)        // 6144
#define BKT   64              // K per tile
#define NT    (DIN / BKT)     // 32 K-tiles

typedef __attribute__((ext_vector_type(8))) short  short8;
typedef __attribute__((ext_vector_type(4))) float  f32x4;
typedef __attribute__((ext_vector_type(4))) ushort ushort4v;

typedef const __attribute__((address_space(1))) void* gas_ptr;
typedef __attribute__((address_space(3))) void*       las_ptr;

#define GLOAD16(g, l) __builtin_amdgcn_global_load_lds((gas_ptr)(g), (las_ptr)(l), 16, 0, 0)

__device__ __forceinline__ float bf2f(ushort u) {
    return __uint_as_float(((uint32_t)u) << 16);
}
__device__ __forceinline__ ushort f2bf(float f) {
    uint32_t u = __float_as_uint(f);
    uint32_t r = u + 0x7FFFu + ((u >> 16) & 1u);  // RNE
    return (ushort)(r >> 16);
}

// ---------------- K0: fused  x f32->bf16  +  W transpose/deinterleave ----------------
__global__ __launch_bounds__(256) void pre_kernel(const f32x4* __restrict__ x4,
                                                  ushort4v* __restrict__ xb4,
                                                  const float* __restrict__ W,
                                                  ushort* __restrict__ WT) {
    __shared__ float tile[64][65];
    int bid = blockIdx.x;
    if (bid < 2048) {
        int i = bid * 256 + threadIdx.x;
        const int n4 = MROWS * DIN / 4;
        const int stride = 2048 * 256;
        for (; i < n4; i += stride) {
            f32x4 v = x4[i];
            ushort4v o;
            o.x = f2bf(v.x); o.y = f2bf(v.y); o.z = f2bf(v.z); o.w = f2bf(v.w);
            xb4[i] = o;
        }
    } else {
        int b2 = bid - 2048;
        int k0 = (b2 & 31) * 64;
        int n0 = (b2 >> 5) * 64;
        int c  = threadIdx.x & 63;
        int r0 = threadIdx.x >> 6;
#pragma unroll
        for (int rr = 0; rr < 16; ++rr) {
            int r = r0 + rr * 4;
            tile[r][c] = W[(size_t)(k0 + r) * NCOLS + n0 + c];
        }
        __syncthreads();
#pragma unroll
        for (int rr = 0; rr < 16; ++rr) {
            int r = r0 + rr * 4;
            int n = n0 + r;
            int nprime = (n % 3) * DD + (n / 3);
            WT[(size_t)nprime * DIN + k0 + c] = f2bf(tile[c][r]);
        }
    }
}

// ---------------- K1: 256x256 GEMM — ROUND-8 SOURCE VERBATIM (best measured: 415 us) ----
// 16x16x32 swapped-operand MFMA, read-ahead fragments, fenced barriers.
#define SLOT(b, s) (&lds8[(((b) << 2) + (s)) * 8192])

#define STAGE_A(b, h, kt) do {                                                   \
    const ushort* _g = Ab + (size_t)((h) * 64 + idx) * DIN + (kt) * BKT + akc;   \
    ushort* _l = SLOT(b, (h)) + tid * 8;                                         \
    GLOAD16(_g, _l);                                                             \
    GLOAD16(_g + (size_t)128 * DIN, _l + 4096);                                  \
} while (0)

#define STAGE_B(b, h2, kt) do {                                                  \
    const ushort* _g0 = Bb + (size_t)(brow0 + (h2) * 32) * DIN + (kt) * BKT + akc;\
    const ushort* _g1 = Bb + (size_t)(brow1 + (h2) * 32) * DIN + (kt) * BKT + akc;\
    ushort* _l = SLOT(b, 2 + (h2)) + tid * 8;                                    \
    GLOAD16(_g0, _l);                                                            \
    GLOAD16(_g1, _l + 4096);                                                     \
} while (0)

#define LD_A2(dst, b, h) do { const ushort* _s = SLOT(b, (h)) + a_rb;            \
    _Pragma("unroll") for (int _m = 0; _m < 4; ++_m) {                           \
        dst[_m][0] = *(const short8*)(_s + _m * 1024 + cs0);                     \
        dst[_m][1] = *(const short8*)(_s + _m * 1024 + cs1); }                   \
} while (0)

#define LD_B(b, h2, bF) do { const ushort* _s = SLOT(b, 2 + (h2)) + b_rb;        \
    _Pragma("unroll") for (int _n = 0; _n < 2; ++_n) {                           \
        bF[_n][0] = *(const short8*)(_s + _n * 1024 + cs0);                      \
        bF[_n][1] = *(const short8*)(_s + _n * 1024 + cs1); }                    \
} while (0)

#define MM(mb, aR, bF, nb) do {                                                  \
    __builtin_amdgcn_s_setprio(1);                                               \
    _Pragma("unroll") for (int _m = 0; _m < 4; ++_m)                             \
    _Pragma("unroll") for (int _n = 0; _n < 2; ++_n) {                           \
        acc[(mb)+_m][(nb)+_n] = __builtin_amdgcn_mfma_f32_16x16x32_bf16(         \
            bF[_n][0], aR[_m][0], acc[(mb)+_m][(nb)+_n], 0, 0, 0);               \
        acc[(mb)+_m][(nb)+_n] = __builtin_amdgcn_mfma_f32_16x16x32_bf16(         \
            bF[_n][1], aR[_m][1], acc[(mb)+_m][(nb)+_n], 0, 0, 0); }             \
    __builtin_amdgcn_s_setprio(0);                                               \
    __builtin_amdgcn_sched_barrier(0);                                           \
} while (0)

#define BARF() do { __builtin_amdgcn_sched_barrier(0);                           \
    __builtin_amdgcn_s_barrier();                                                \
    __builtin_amdgcn_sched_barrier(0); } while (0)

__global__ __launch_bounds__(512, 2) void sru_gemm8(const ushort* __restrict__ A,
                                                    const ushort* __restrict__ Bt,
                                                    const float*  __restrict__ bias,
                                                    ushort* __restrict__ u0,
                                                    ushort* __restrict__ g1,
                                                    ushort* __restrict__ g2) {
    __shared__ alignas(16) ushort lds8[65536];   // 128 KiB

    int bid = blockIdx.x;                        // 1536 blocks (%8==0 -> bijective swizzle)
    int swz = (bid & 7) * 192 + (bid >> 3);
    int bm0 = (swz / 24) * 256;
    int bn0 = (swz % 24) * 256;

    int tid  = threadIdx.x;
    int wave = tid >> 6, lane = tid & 63;
    int wm = wave >> 2, wn = wave & 3;

    // staging constants (inverse-swizzled source)
    int idx    = tid >> 3;
    int schunk = (tid & 7) ^ (idx & 7);
    int akc    = schunk * 8;
    int brow0  = (idx >> 5) * 64 + (idx & 31);
    int brow1  = ((idx >> 5) + 2) * 64 + (idx & 31);
    const ushort* Ab = A  + (size_t)bm0 * DIN;
    const ushort* Bb = Bt + (size_t)bn0 * DIN;

    // fragment-read constants (swizzled ds_read)
    int lrow = lane & 15, lk = lane >> 4, lx = lane & 7;
    int cs0  = ((0 + lk) ^ lx) * 8;
    int cs1  = ((4 + lk) ^ lx) * 8;
    int a_rb = (wm * 64 + lrow) * 64;
    int b_rb = (wn * 32 + lrow) * 64;

    f32x4 acc[8][4];
    f32x4 zero = {0.f, 0.f, 0.f, 0.f};
#pragma unroll
    for (int i = 0; i < 8; ++i)
#pragma unroll
        for (int j = 0; j < 4; ++j) acc[i][j] = zero;

    // prologue: tile0 fully + tile1's A0,B0; wait tile0 landed (outstanding = 4);
    // pre-read aFA (= steady-state ph3-end read)
    STAGE_A(0, 0, 0); STAGE_A(0, 1, 0); STAGE_B(0, 0, 0); STAGE_B(0, 1, 0);
    STAGE_A(1, 0, 1); STAGE_B(1, 0, 1);
    asm volatile("s_waitcnt vmcnt(4)" ::: "memory");
    BARF();

    short8 aFA[4][2], aFB[4][2], bF0[2][2], bF1[2][2];
    LD_A2(aFA, 0, 0);
    __builtin_amdgcn_sched_barrier(0);

    for (int t = 0; t < NT; ++t) {
        int cur = t & 1, nxt = cur ^ 1;
        // ph0: read bF0 (this phase) + bF1 (ahead, ph1); MM(A0xB0)
        LD_B(cur, 0, bF0);
        LD_B(cur, 1, bF1);
        STAGE_A(nxt, 1, t + 1);
        BARF(); MM(0, aFA, bF0, 0); BARF();
        // ph1: read aFB (ahead, ph2/ph3); MM(A0xB1)
        LD_A2(aFB, cur, 1);
        STAGE_B(nxt, 1, t + 1);
        BARF(); MM(0, aFA, bF1, 2); BARF();
        // ph2: no reads; MM(A1xB0)
        STAGE_A(cur, 0, t + 2);
        BARF(); MM(4, aFB, bF0, 0); BARF();
        // ph3: stage B0(t+2); vmcnt(4) proves tile t+1 landed; read next aFA; MM(A1xB1)
        STAGE_B(cur, 0, t + 2);
        asm volatile("s_waitcnt vmcnt(4)" ::: "memory");
        BARF();
        LD_A2(aFA, nxt, 0);
        MM(4, aFB, bF1, 2);
        BARF();
    }
    asm volatile("s_waitcnt vmcnt(0)" ::: "memory");  // drain dead stages

    // epilogue (swapped layout): acc[h*4+i][j] -> row = bm0 + wm*128 + h*64 + i*16 + (lane&15),
    // cols = bn0' + wn*64 + j*16 + (lane>>4)*4 + {0..3} -> pack 4 bf16, one 8B store
    int region = bn0 >> 11;                      // 0:u0 1:g1 2:g2
    int colb = (bn0 & (DD - 1)) + wn * 64 + ((lane >> 4) << 2);
    int rowm = bm0 + wm * 128 + (lane & 15);
    if (region == 0) {
#pragma unroll
        for (int j = 0; j < 4; ++j)
#pragma unroll
            for (int i = 0; i < 4; ++i) {
                f32x4 v = acc[i][j];
                uint32_t lo, hi;
                asm("v_cvt_pk_bf16_f32 %0, %1, %2" : "=v"(lo) : "v"(v[0]), "v"(v[1]));
                asm("v_cvt_pk_bf16_f32 %0, %1, %2" : "=v"(hi) : "v"(v[2]), "v"(v[3]));
                uint2 pk; pk.x = lo; pk.y = hi;
                *(uint2*)&u0[(size_t)(rowm + i * 16) * DD + colb + j * 16] = pk;
                f32x4 w = acc[4 + i][j];
                asm("v_cvt_pk_bf16_f32 %0, %1, %2" : "=v"(lo) : "v"(w[0]), "v"(w[1]));
                asm("v_cvt_pk_bf16_f32 %0, %1, %2" : "=v"(hi) : "v"(w[2]), "v"(w[3]));
                pk.x = lo; pk.y = hi;
                *(uint2*)&u0[(size_t)(rowm + 64 + i * 16) * DD + colb + j * 16] = pk;
            }
    } else {
        const float* bp = bias + (size_t)(region - 1) * DD;
        ushort* gp = (region == 1) ? g1 : g2;
#pragma unroll
        for (int j = 0; j < 4; ++j) {
            float4 bv = *(const float4*)&bp[colb + j * 16];
#pragma unroll
            for (int i = 0; i < 8; ++i) {
                f32x4 v = acc[i][j];
                float s0 = 1.f / (1.f + __expf(-(v[0] + bv.x)));
                float s1 = 1.f / (1.f + __expf(-(v[1] + bv.y)));
                float s2 = 1.f / (1.f + __expf(-(v[2] + bv.z)));
                float s3 = 1.f / (1.f + __expf(-(v[3] + bv.w)));
                uint32_t lo, hi;
                asm("v_cvt_pk_bf16_f32 %0, %1, %2" : "=v"(lo) : "v"(s0), "v"(s1));
                asm("v_cvt_pk_bf16_f32 %0, %1, %2" : "=v"(hi) : "v"(s2), "v"(s3));
                uint2 pk; pk.x = lo; pk.y = hi;
                int rr = rowm + (i >> 2) * 64 + (i & 3) * 16;
                *(uint2*)&gp[(size_t)rr * DD + colb + j * 16] = pk;
            }
        }
    }
}

// ---------------- K2: recurrence, 2 chains/thread, 4B packed loads, float2 stores ----------
__global__ __launch_bounds__(64) void sru_rec2(const uint32_t* __restrict__ u0,
                                               const uint32_t* __restrict__ g1,
                                               const uint32_t* __restrict__ g2,
                                               const uint32_t* __restrict__ xb,
                                               const float*  __restrict__ c0,
                                               float* __restrict__ h,
                                               float* __restrict__ c_last) {
    int t2 = blockIdx.x * 64 + threadIdx.x;   // 0..16383: pair index (b*DD + d)/2
    float ca = c0[t2 * 2], cb = c0[t2 * 2 + 1];
#pragma unroll 16
    for (int l = 0; l < L_SEQ; ++l) {
        int ix = l * (BSZ * DD / 2) + t2;     // uint index
        uint32_t pu = u0[ix], p1 = g1[ix], p2 = g2[ix], px = xb[ix];
        float ua = bf2f((ushort)pu),        ub = bf2f((ushort)(pu >> 16));
        float ga = bf2f((ushort)p1),        gb = bf2f((ushort)(p1 >> 16));
        float ra = bf2f((ushort)p2),        rb2 = bf2f((ushort)(p2 >> 16));
        float xa = bf2f((ushort)px),        xbv = bf2f((ushort)(px >> 16));
        ca = (ca - ua) * ga + ua;
        cb = (cb - ub) * gb + ub;
        float ea = __expf(-2.f * fabsf(ca));
        float eb = __expf(-2.f * fabsf(cb));
        float ta = copysignf((1.f - ea) / (1.f + ea), ca);
        float tb = copysignf((1.f - eb) / (1.f + eb), cb);
        float2 hv;
        hv.x = (ta - xa) * ra + xa;
        hv.y = (tb - xbv) * rb2 + xbv;
        *(float2*)&h[(size_t)ix * 2] = hv;
    }
    c_last[t2 * 2]     = ca;
    c_last[t2 * 2 + 1] = cb;
}

extern "C" void kernel_launch(void* const* d_in, const int* in_sizes, int n_in,
                              void* d_out, int out_size, void* d_ws, size_t ws_size,
                              hipStream_t stream) {
    const float* x    = (const float*)d_in[0];
    const float* c0   = (const float*)d_in[1];
    const float* W    = (const float*)d_in[2];
    const float* bias = (const float*)d_in[3];
    float* out = (float*)d_out;

    char* ws = (char*)d_ws;
    ushort* xb = (ushort*)(ws);                       //  67,108,864 B  (x bf16)
    ushort* WT = (ushort*)(ws + 67108864);            //  25,165,824 B  (W^T bf16, deinterleaved)
    ushort* u0 = (ushort*)(ws + 92274688);            //  67,108,864 B  (u0 bf16)
    ushort* g1 = (ushort*)(ws + 159383552);           //  67,108,864 B
    ushort* g2 = (ushort*)(ws + 226492416);           //  67,108,864 B  -> 293,601,280 total

    hipLaunchKernelGGL(pre_kernel, dim3(5120), dim3(256), 0, stream,
                       (const f32x4*)x, (ushort4v*)xb, W, WT);
    hipLaunchKernelGGL(sru_gemm8, dim3(1536), dim3(512), 0, stream, xb, WT, bias, u0, g1, g2);
    hipLaunchKernelGGL(sru_rec2, dim3(256), dim3(64), 0, stream,
                       (const uint32_t*)u0, (const uint32_t*)g1, (const uint32_t*)g2,
                       (const uint32_t*)xb, c0, out, out + (size_t)MROWS * DD);
}

// Round 12
// 679.463 us; speedup vs baseline: 1.3574x; 1.3574x over previous
//
#include <hip/hip_runtime.h>
#include <hip/hip_bf16.h>
#include <cstdint>

#define L_SEQ 1024
#define BSZ   16
#define DIN   2048
#define DD    2048
#define MROWS (L_SEQ * BSZ)   // 16384
#define NCOLS (3 * DD)        // 6144
#define BKT   64              // K per tile
#define NT    (DIN / BKT)     // 32 K-tiles

typedef __attribute__((ext_vector_type(8))) short  short8;
typedef __attribute__((ext_vector_type(4))) float  f32x4;
typedef __attribute__((ext_vector_type(4))) ushort ushort4v;

typedef const __attribute__((address_space(1))) void* gas_ptr;
typedef __attribute__((address_space(3))) void*       las_ptr;

#define GLOAD16(g, l) __builtin_amdgcn_global_load_lds((gas_ptr)(g), (las_ptr)(l), 16, 0, 0)

__device__ __forceinline__ float bf2f(ushort u) {
    return __uint_as_float(((uint32_t)u) << 16);
}
__device__ __forceinline__ ushort f2bf(float f) {
    uint32_t u = __float_as_uint(f);
    uint32_t r = u + 0x7FFFu + ((u >> 16) & 1u);  // RNE
    return (ushort)(r >> 16);
}

// ---------------- K0: fused  x f32->bf16  +  W transpose/deinterleave ----------------
__global__ __launch_bounds__(256) void pre_kernel(const f32x4* __restrict__ x4,
                                                  ushort4v* __restrict__ xb4,
                                                  const float* __restrict__ W,
                                                  ushort* __restrict__ WT) {
    __shared__ float tile[64][65];
    int bid = blockIdx.x;
    if (bid < 2048) {
        int i = bid * 256 + threadIdx.x;
        const int n4 = MROWS * DIN / 4;
        const int stride = 2048 * 256;
        for (; i < n4; i += stride) {
            f32x4 v = x4[i];
            ushort4v o;
            o.x = f2bf(v.x); o.y = f2bf(v.y); o.z = f2bf(v.z); o.w = f2bf(v.w);
            xb4[i] = o;
        }
    } else {
        int b2 = bid - 2048;
        int k0 = (b2 & 31) * 64;
        int n0 = (b2 >> 5) * 64;
        int c  = threadIdx.x & 63;
        int r0 = threadIdx.x >> 6;
#pragma unroll
        for (int rr = 0; rr < 16; ++rr) {
            int r = r0 + rr * 4;
            tile[r][c] = W[(size_t)(k0 + r) * NCOLS + n0 + c];
        }
        __syncthreads();
#pragma unroll
        for (int rr = 0; rr < 16; ++rr) {
            int r = r0 + rr * 4;
            int n = n0 + r;
            int nprime = (n % 3) * DD + (n / 3);
            WT[(size_t)nprime * DIN + k0 + c] = f2bf(tile[c][r]);
        }
    }
}

// ---------------- K1: 256x256 GEMM — ROUND-8 SOURCE VERBATIM (best measured: 415 us) ----
#define SLOT(b, s) (&lds8[(((b) << 2) + (s)) * 8192])

#define STAGE_A(b, h, kt) do {                                                   \
    const ushort* _g = Ab + (size_t)((h) * 64 + idx) * DIN + (kt) * BKT + akc;   \
    ushort* _l = SLOT(b, (h)) + tid * 8;                                         \
    GLOAD16(_g, _l);                                                             \
    GLOAD16(_g + (size_t)128 * DIN, _l + 4096);                                  \
} while (0)

#define STAGE_B(b, h2, kt) do {                                                  \
    const ushort* _g0 = Bb + (size_t)(brow0 + (h2) * 32) * DIN + (kt) * BKT + akc;\
    const ushort* _g1 = Bb + (size_t)(brow1 + (h2) * 32) * DIN + (kt) * BKT + akc;\
    ushort* _l = SLOT(b, 2 + (h2)) + tid * 8;                                    \
    GLOAD16(_g0, _l);                                                            \
    GLOAD16(_g1, _l + 4096);                                                     \
} while (0)

#define LD_A2(dst, b, h) do { const ushort* _s = SLOT(b, (h)) + a_rb;            \
    _Pragma("unroll") for (int _m = 0; _m < 4; ++_m) {                           \
        dst[_m][0] = *(const short8*)(_s + _m * 1024 + cs0);                     \
        dst[_m][1] = *(const short8*)(_s + _m * 1024 + cs1); }                   \
} while (0)

#define LD_B(b, h2, bF) do { const ushort* _s = SLOT(b, 2 + (h2)) + b_rb;        \
    _Pragma("unroll") for (int _n = 0; _n < 2; ++_n) {                           \
        bF[_n][0] = *(const short8*)(_s + _n * 1024 + cs0);                      \
        bF[_n][1] = *(const short8*)(_s + _n * 1024 + cs1); }                    \
} while (0)

#define MM(mb, aR, bF, nb) do {                                                  \
    __builtin_amdgcn_s_setprio(1);                                               \
    _Pragma("unroll") for (int _m = 0; _m < 4; ++_m)                             \
    _Pragma("unroll") for (int _n = 0; _n < 2; ++_n) {                           \
        acc[(mb)+_m][(nb)+_n] = __builtin_amdgcn_mfma_f32_16x16x32_bf16(         \
            bF[_n][0], aR[_m][0], acc[(mb)+_m][(nb)+_n], 0, 0, 0);               \
        acc[(mb)+_m][(nb)+_n] = __builtin_amdgcn_mfma_f32_16x16x32_bf16(         \
            bF[_n][1], aR[_m][1], acc[(mb)+_m][(nb)+_n], 0, 0, 0); }             \
    __builtin_amdgcn_s_setprio(0);                                               \
    __builtin_amdgcn_sched_barrier(0);                                           \
} while (0)

#define BARF() do { __builtin_amdgcn_sched_barrier(0);                           \
    __builtin_amdgcn_s_barrier();                                                \
    __builtin_amdgcn_sched_barrier(0); } while (0)

__global__ __launch_bounds__(512, 2) void sru_gemm8(const ushort* __restrict__ A,
                                                    const ushort* __restrict__ Bt,
                                                    const float*  __restrict__ bias,
                                                    ushort* __restrict__ u0,
                                                    ushort* __restrict__ g1,
                                                    ushort* __restrict__ g2) {
    __shared__ alignas(16) ushort lds8[65536];   // 128 KiB

    int bid = blockIdx.x;                        // 1536 blocks (%8==0 -> bijective swizzle)
    int swz = (bid & 7) * 192 + (bid >> 3);
    int bm0 = (swz / 24) * 256;
    int bn0 = (swz % 24) * 256;

    int tid  = threadIdx.x;
    int wave = tid >> 6, lane = tid & 63;
    int wm = wave >> 2, wn = wave & 3;

    int idx    = tid >> 3;
    int schunk = (tid & 7) ^ (idx & 7);
    int akc    = schunk * 8;
    int brow0  = (idx >> 5) * 64 + (idx & 31);
    int brow1  = ((idx >> 5) + 2) * 64 + (idx & 31);
    const ushort* Ab = A  + (size_t)bm0 * DIN;
    const ushort* Bb = Bt + (size_t)bn0 * DIN;

    int lrow = lane & 15, lk = lane >> 4, lx = lane & 7;
    int cs0  = ((0 + lk) ^ lx) * 8;
    int cs1  = ((4 + lk) ^ lx) * 8;
    int a_rb = (wm * 64 + lrow) * 64;
    int b_rb = (wn * 32 + lrow) * 64;

    f32x4 acc[8][4];
    f32x4 zero = {0.f, 0.f, 0.f, 0.f};
#pragma unroll
    for (int i = 0; i < 8; ++i)
#pragma unroll
        for (int j = 0; j < 4; ++j) acc[i][j] = zero;

    STAGE_A(0, 0, 0); STAGE_A(0, 1, 0); STAGE_B(0, 0, 0); STAGE_B(0, 1, 0);
    STAGE_A(1, 0, 1); STAGE_B(1, 0, 1);
    asm volatile("s_waitcnt vmcnt(4)" ::: "memory");
    BARF();

    short8 aFA[4][2], aFB[4][2], bF0[2][2], bF1[2][2];
    LD_A2(aFA, 0, 0);
    __builtin_amdgcn_sched_barrier(0);

    for (int t = 0; t < NT; ++t) {
        int cur = t & 1, nxt = cur ^ 1;
        LD_B(cur, 0, bF0);
        LD_B(cur, 1, bF1);
        STAGE_A(nxt, 1, t + 1);
        BARF(); MM(0, aFA, bF0, 0); BARF();
        LD_A2(aFB, cur, 1);
        STAGE_B(nxt, 1, t + 1);
        BARF(); MM(0, aFA, bF1, 2); BARF();
        STAGE_A(cur, 0, t + 2);
        BARF(); MM(4, aFB, bF0, 0); BARF();
        STAGE_B(cur, 0, t + 2);
        asm volatile("s_waitcnt vmcnt(4)" ::: "memory");
        BARF();
        LD_A2(aFA, nxt, 0);
        MM(4, aFB, bF1, 2);
        BARF();
    }
    asm volatile("s_waitcnt vmcnt(0)" ::: "memory");

    int region = bn0 >> 11;                      // 0:u0 1:g1 2:g2
    int colb = (bn0 & (DD - 1)) + wn * 64 + ((lane >> 4) << 2);
    int rowm = bm0 + wm * 128 + (lane & 15);
    if (region == 0) {
#pragma unroll
        for (int j = 0; j < 4; ++j)
#pragma unroll
            for (int i = 0; i < 4; ++i) {
                f32x4 v = acc[i][j];
                uint32_t lo, hi;
                asm("v_cvt_pk_bf16_f32 %0, %1, %2" : "=v"(lo) : "v"(v[0]), "v"(v[1]));
                asm("v_cvt_pk_bf16_f32 %0, %1, %2" : "=v"(hi) : "v"(v[2]), "v"(v[3]));
                uint2 pk; pk.x = lo; pk.y = hi;
                *(uint2*)&u0[(size_t)(rowm + i * 16) * DD + colb + j * 16] = pk;
                f32x4 w = acc[4 + i][j];
                asm("v_cvt_pk_bf16_f32 %0, %1, %2" : "=v"(lo) : "v"(w[0]), "v"(w[1]));
                asm("v_cvt_pk_bf16_f32 %0, %1, %2" : "=v"(hi) : "v"(w[2]), "v"(w[3]));
                pk.x = lo; pk.y = hi;
                *(uint2*)&u0[(size_t)(rowm + 64 + i * 16) * DD + colb + j * 16] = pk;
            }
    } else {
        const float* bp = bias + (size_t)(region - 1) * DD;
        ushort* gp = (region == 1) ? g1 : g2;
#pragma unroll
        for (int j = 0; j < 4; ++j) {
            float4 bv = *(const float4*)&bp[colb + j * 16];
#pragma unroll
            for (int i = 0; i < 8; ++i) {
                f32x4 v = acc[i][j];
                float s0 = 1.f / (1.f + __expf(-(v[0] + bv.x)));
                float s1 = 1.f / (1.f + __expf(-(v[1] + bv.y)));
                float s2 = 1.f / (1.f + __expf(-(v[2] + bv.z)));
                float s3 = 1.f / (1.f + __expf(-(v[3] + bv.w)));
                uint32_t lo, hi;
                asm("v_cvt_pk_bf16_f32 %0, %1, %2" : "=v"(lo) : "v"(s0), "v"(s1));
                asm("v_cvt_pk_bf16_f32 %0, %1, %2" : "=v"(hi) : "v"(s2), "v"(s3));
                uint2 pk; pk.x = lo; pk.y = hi;
                int rr = rowm + (i >> 2) * 64 + (i & 3) * 16;
                *(uint2*)&gp[(size_t)rr * DD + colb + j * 16] = pk;
            }
        }
    }
}

// ---------------- K2: recurrence, 1 chain/thread, explicit 16-step prefetch chunks ------
// 512 blocks x 64 thr = 2 waves/CU. Per chunk: issue all 64 scalar loads (4 streams x 16)
// before computing -> ~8KB/wave in flight, covers ~900cyc HBM latency at 2 waves/CU.
#define RCHUNK 16
__global__ __launch_bounds__(64) void sru_rec(const ushort* __restrict__ u0,
                                              const ushort* __restrict__ g1,
                                              const ushort* __restrict__ g2,
                                              const ushort* __restrict__ xb,
                                              const float*  __restrict__ c0,
                                              float* __restrict__ h,
                                              float* __restrict__ c_last) {
    const int STR = BSZ * DD;
    int t = blockIdx.x * 64 + threadIdx.x;   // t = b*DD + d
    float c = c0[t];
    const ushort* pu = u0 + t;
    const ushort* p1 = g1 + t;
    const ushort* p2 = g2 + t;
    const ushort* px = xb + t;
    float* ph = h + t;
    for (int l0 = 0; l0 < L_SEQ; l0 += RCHUNK) {
        ushort bu[RCHUNK], b1[RCHUNK], b2[RCHUNK], bx[RCHUNK];
#pragma unroll
        for (int j = 0; j < RCHUNK; ++j) {
            int ix = (l0 + j) * STR;
            bu[j] = pu[ix]; b1[j] = p1[ix]; b2[j] = p2[ix]; bx[j] = px[ix];
        }
#pragma unroll
        for (int j = 0; j < RCHUNK; ++j) {
            float uu  = bf2f(bu[j]);
            float gg1 = bf2f(b1[j]);
            float gg2 = bf2f(b2[j]);
            float xx  = bf2f(bx[j]);
            c = (c - uu) * gg1 + uu;
            float e  = __expf(-2.f * fabsf(c));
            float th = (1.f - e) / (1.f + e);
            th = copysignf(th, c);
            ph[(l0 + j) * STR] = (th - xx) * gg2 + xx;
        }
    }
    c_last[t] = c;
}

extern "C" void kernel_launch(void* const* d_in, const int* in_sizes, int n_in,
                              void* d_out, int out_size, void* d_ws, size_t ws_size,
                              hipStream_t stream) {
    const float* x    = (const float*)d_in[0];
    const float* c0   = (const float*)d_in[1];
    const float* W    = (const float*)d_in[2];
    const float* bias = (const float*)d_in[3];
    float* out = (float*)d_out;

    char* ws = (char*)d_ws;
    ushort* xb = (ushort*)(ws);                       //  67,108,864 B  (x bf16)
    ushort* WT = (ushort*)(ws + 67108864);            //  25,165,824 B  (W^T bf16, deinterleaved)
    ushort* u0 = (ushort*)(ws + 92274688);            //  67,108,864 B  (u0 bf16)
    ushort* g1 = (ushort*)(ws + 159383552);           //  67,108,864 B
    ushort* g2 = (ushort*)(ws + 226492416);           //  67,108,864 B  -> 293,601,280 total

    hipLaunchKernelGGL(pre_kernel, dim3(5120), dim3(256), 0, stream,
                       (const f32x4*)x, (ushort4v*)xb, W, WT);
    hipLaunchKernelGGL(sru_gemm8, dim3(1536), dim3(512), 0, stream, xb, WT, bias, u0, g1, g2);
    hipLaunchKernelGGL(sru_rec, dim3(512), dim3(64), 0, stream,
                       u0, g1, g2, xb, c0, out, out + (size_t)MROWS * DD);
}

// Round 14
// 627.510 us; speedup vs baseline: 1.4697x; 1.0828x over previous
//
#include <hip/hip_runtime.h>
#include <hip/hip_bf16.h>
#include <cstdint>

#define L_SEQ 1024
#define BSZ   16
#define DIN   2048
#define DD    2048
#define MROWS (L_SEQ * BSZ)   // 16384
#define NCOLS (3 * DD)        // 6144
#define BKT   64              // K per tile
#define NT    (DIN / BKT)     // 32 K-tiles

typedef __attribute__((ext_vector_type(8))) short  short8;
typedef __attribute__((ext_vector_type(4))) float  f32x4;
typedef __attribute__((ext_vector_type(4))) ushort ushort4v;
typedef __attribute__((ext_vector_type(2))) uint32_t u32x2;

typedef const __attribute__((address_space(1))) void* gas_ptr;
typedef __attribute__((address_space(3))) void*       las_ptr;

#define GLOAD16(g, l) __builtin_amdgcn_global_load_lds((gas_ptr)(g), (las_ptr)(l), 16, 0, 0)

__device__ __forceinline__ float bf2f(ushort u) {
    return __uint_as_float(((uint32_t)u) << 16);
}
__device__ __forceinline__ ushort f2bf(float f) {
    uint32_t u = __float_as_uint(f);
    uint32_t r = u + 0x7FFFu + ((u >> 16) & 1u);  // RNE
    return (ushort)(r >> 16);
}

// ---------------- K0: fused  x f32->bf16  +  W transpose/deinterleave ----------------
__global__ __launch_bounds__(256) void pre_kernel(const f32x4* __restrict__ x4,
                                                  ushort4v* __restrict__ xb4,
                                                  const float* __restrict__ W,
                                                  ushort* __restrict__ WT) {
    __shared__ float tile[64][65];
    int bid = blockIdx.x;
    if (bid < 2048) {
        int i = bid * 256 + threadIdx.x;
        const int n4 = MROWS * DIN / 4;
        const int stride = 2048 * 256;
        for (; i < n4; i += stride) {
            f32x4 v = x4[i];
            ushort4v o;
            o.x = f2bf(v.x); o.y = f2bf(v.y); o.z = f2bf(v.z); o.w = f2bf(v.w);
            xb4[i] = o;
        }
    } else {
        int b2 = bid - 2048;
        int k0 = (b2 & 31) * 64;
        int n0 = (b2 >> 5) * 64;
        int c  = threadIdx.x & 63;
        int r0 = threadIdx.x >> 6;
#pragma unroll
        for (int rr = 0; rr < 16; ++rr) {
            int r = r0 + rr * 4;
            tile[r][c] = W[(size_t)(k0 + r) * NCOLS + n0 + c];
        }
        __syncthreads();
#pragma unroll
        for (int rr = 0; rr < 16; ++rr) {
            int r = r0 + rr * 4;
            int n = n0 + r;
            int nprime = (n % 3) * DD + (n / 3);
            WT[(size_t)nprime * DIN + k0 + c] = f2bf(tile[c][r]);
        }
    }
}

// ---------------- K1: 256x256 GEMM — round-8 schedule + NON-TEMPORAL epilogue stores ----
#define SLOT(b, s) (&lds8[(((b) << 2) + (s)) * 8192])

#define STAGE_A(b, h, kt) do {                                                   \
    const ushort* _g = Ab + (size_t)((h) * 64 + idx) * DIN + (kt) * BKT + akc;   \
    ushort* _l = SLOT(b, (h)) + tid * 8;                                         \
    GLOAD16(_g, _l);                                                             \
    GLOAD16(_g + (size_t)128 * DIN, _l + 4096);                                  \
} while (0)

#define STAGE_B(b, h2, kt) do {                                                  \
    const ushort* _g0 = Bb + (size_t)(brow0 + (h2) * 32) * DIN + (kt) * BKT + akc;\
    const ushort* _g1 = Bb + (size_t)(brow1 + (h2) * 32) * DIN + (kt) * BKT + akc;\
    ushort* _l = SLOT(b, 2 + (h2)) + tid * 8;                                    \
    GLOAD16(_g0, _l);                                                            \
    GLOAD16(_g1, _l + 4096);                                                     \
} while (0)

#define LD_A2(dst, b, h) do { const ushort* _s = SLOT(b, (h)) + a_rb;            \
    _Pragma("unroll") for (int _m = 0; _m < 4; ++_m) {                           \
        dst[_m][0] = *(const short8*)(_s + _m * 1024 + cs0);                     \
        dst[_m][1] = *(const short8*)(_s + _m * 1024 + cs1); }                   \
} while (0)

#define LD_B(b, h2, bF) do { const ushort* _s = SLOT(b, 2 + (h2)) + b_rb;        \
    _Pragma("unroll") for (int _n = 0; _n < 2; ++_n) {                           \
        bF[_n][0] = *(const short8*)(_s + _n * 1024 + cs0);                      \
        bF[_n][1] = *(const short8*)(_s + _n * 1024 + cs1); }                    \
} while (0)

#define MM(mb, aR, bF, nb) do {                                                  \
    __builtin_amdgcn_s_setprio(1);                                               \
    _Pragma("unroll") for (int _m = 0; _m < 4; ++_m)                             \
    _Pragma("unroll") for (int _n = 0; _n < 2; ++_n) {                           \
        acc[(mb)+_m][(nb)+_n] = __builtin_amdgcn_mfma_f32_16x16x32_bf16(         \
            bF[_n][0], aR[_m][0], acc[(mb)+_m][(nb)+_n], 0, 0, 0);               \
        acc[(mb)+_m][(nb)+_n] = __builtin_amdgcn_mfma_f32_16x16x32_bf16(         \
            bF[_n][1], aR[_m][1], acc[(mb)+_m][(nb)+_n], 0, 0, 0); }             \
    __builtin_amdgcn_s_setprio(0);                                               \
    __builtin_amdgcn_sched_barrier(0);                                           \
} while (0)

#define BARF() do { __builtin_amdgcn_sched_barrier(0);                           \
    __builtin_amdgcn_s_barrier();                                                \
    __builtin_amdgcn_sched_barrier(0); } while (0)

__global__ __launch_bounds__(512, 2) void sru_gemm8(const ushort* __restrict__ A,
                                                    const ushort* __restrict__ Bt,
                                                    const float*  __restrict__ bias,
                                                    ushort* __restrict__ u0,
                                                    ushort* __restrict__ g1,
                                                    ushort* __restrict__ g2) {
    __shared__ alignas(16) ushort lds8[65536];   // 128 KiB

    int bid = blockIdx.x;                        // 1536 blocks (%8==0 -> bijective swizzle)
    int swz = (bid & 7) * 192 + (bid >> 3);
    int bm0 = (swz / 24) * 256;
    int bn0 = (swz % 24) * 256;

    int tid  = threadIdx.x;
    int wave = tid >> 6, lane = tid & 63;
    int wm = wave >> 2, wn = wave & 3;

    int idx    = tid >> 3;
    int schunk = (tid & 7) ^ (idx & 7);
    int akc    = schunk * 8;
    int brow0  = (idx >> 5) * 64 + (idx & 31);
    int brow1  = ((idx >> 5) + 2) * 64 + (idx & 31);
    const ushort* Ab = A  + (size_t)bm0 * DIN;
    const ushort* Bb = Bt + (size_t)bn0 * DIN;

    int lrow = lane & 15, lk = lane >> 4, lx = lane & 7;
    int cs0  = ((0 + lk) ^ lx) * 8;
    int cs1  = ((4 + lk) ^ lx) * 8;
    int a_rb = (wm * 64 + lrow) * 64;
    int b_rb = (wn * 32 + lrow) * 64;

    f32x4 acc[8][4];
    f32x4 zero = {0.f, 0.f, 0.f, 0.f};
#pragma unroll
    for (int i = 0; i < 8; ++i)
#pragma unroll
        for (int j = 0; j < 4; ++j) acc[i][j] = zero;

    STAGE_A(0, 0, 0); STAGE_A(0, 1, 0); STAGE_B(0, 0, 0); STAGE_B(0, 1, 0);
    STAGE_A(1, 0, 1); STAGE_B(1, 0, 1);
    asm volatile("s_waitcnt vmcnt(4)" ::: "memory");
    BARF();

    short8 aFA[4][2], aFB[4][2], bF0[2][2], bF1[2][2];
    LD_A2(aFA, 0, 0);
    __builtin_amdgcn_sched_barrier(0);

    for (int t = 0; t < NT; ++t) {
        int cur = t & 1, nxt = cur ^ 1;
        LD_B(cur, 0, bF0);
        LD_B(cur, 1, bF1);
        STAGE_A(nxt, 1, t + 1);
        BARF(); MM(0, aFA, bF0, 0); BARF();
        LD_A2(aFB, cur, 1);
        STAGE_B(nxt, 1, t + 1);
        BARF(); MM(0, aFA, bF1, 2); BARF();
        STAGE_A(cur, 0, t + 2);
        BARF(); MM(4, aFB, bF0, 0); BARF();
        STAGE_B(cur, 0, t + 2);
        asm volatile("s_waitcnt vmcnt(4)" ::: "memory");
        BARF();
        LD_A2(aFA, nxt, 0);
        MM(4, aFB, bF1, 2);
        BARF();
    }
    asm volatile("s_waitcnt vmcnt(0)" ::: "memory");

    // epilogue: non-temporal 8B stores (don't evict A/B panels from L2/L3)
    int region = bn0 >> 11;                      // 0:u0 1:g1 2:g2
    int colb = (bn0 & (DD - 1)) + wn * 64 + ((lane >> 4) << 2);
    int rowm = bm0 + wm * 128 + (lane & 15);
    if (region == 0) {
#pragma unroll
        for (int j = 0; j < 4; ++j)
#pragma unroll
            for (int i = 0; i < 4; ++i) {
                f32x4 v = acc[i][j];
                uint32_t lo, hi;
                asm("v_cvt_pk_bf16_f32 %0, %1, %2" : "=v"(lo) : "v"(v[0]), "v"(v[1]));
                asm("v_cvt_pk_bf16_f32 %0, %1, %2" : "=v"(hi) : "v"(v[2]), "v"(v[3]));
                u32x2 pk; pk.x = lo; pk.y = hi;
                __builtin_nontemporal_store(pk,
                    (u32x2*)&u0[(size_t)(rowm + i * 16) * DD + colb + j * 16]);
                f32x4 w = acc[4 + i][j];
                asm("v_cvt_pk_bf16_f32 %0, %1, %2" : "=v"(lo) : "v"(w[0]), "v"(w[1]));
                asm("v_cvt_pk_bf16_f32 %0, %1, %2" : "=v"(hi) : "v"(w[2]), "v"(w[3]));
                pk.x = lo; pk.y = hi;
                __builtin_nontemporal_store(pk,
                    (u32x2*)&u0[(size_t)(rowm + 64 + i * 16) * DD + colb + j * 16]);
            }
    } else {
        const float* bp = bias + (size_t)(region - 1) * DD;
        ushort* gp = (region == 1) ? g1 : g2;
#pragma unroll
        for (int j = 0; j < 4; ++j) {
            float4 bv = *(const float4*)&bp[colb + j * 16];
#pragma unroll
            for (int i = 0; i < 8; ++i) {
                f32x4 v = acc[i][j];
                float s0 = 1.f / (1.f + __expf(-(v[0] + bv.x)));
                float s1 = 1.f / (1.f + __expf(-(v[1] + bv.y)));
                float s2 = 1.f / (1.f + __expf(-(v[2] + bv.z)));
                float s3 = 1.f / (1.f + __expf(-(v[3] + bv.w)));
                uint32_t lo, hi;
                asm("v_cvt_pk_bf16_f32 %0, %1, %2" : "=v"(lo) : "v"(s0), "v"(s1));
                asm("v_cvt_pk_bf16_f32 %0, %1, %2" : "=v"(hi) : "v"(s2), "v"(s3));
                u32x2 pk; pk.x = lo; pk.y = hi;
                int rr = rowm + (i >> 2) * 64 + (i & 3) * 16;
                __builtin_nontemporal_store(pk,
                    (u32x2*)&gp[(size_t)rr * DD + colb + j * 16]);
            }
        }
    }
}

// ---------------- K2: recurrence — ROUND-8 FORM VERBATIM (best measured ~107 us) --------
__global__ __launch_bounds__(64) void sru_rec(const ushort* __restrict__ u0,
                                              const ushort* __restrict__ g1,
                                              const ushort* __restrict__ g2,
                                              const ushort* __restrict__ xb,
                                              const float*  __restrict__ c0,
                                              float* __restrict__ h,
                                              float* __restrict__ c_last) {
    int t = blockIdx.x * 64 + threadIdx.x;   // t = b*DD + d
    float c = c0[t];
#pragma unroll 16
    for (int l = 0; l < L_SEQ; ++l) {
        int ix = l * (BSZ * DD) + t;
        float uu  = bf2f(u0[ix]);
        float gg1 = bf2f(g1[ix]);
        float gg2 = bf2f(g2[ix]);
        float xx  = bf2f(xb[ix]);
        c = (c - uu) * gg1 + uu;
        float e  = __expf(-2.f * fabsf(c));
        float th = (1.f - e) / (1.f + e);
        th = copysignf(th, c);
        h[ix] = (th - xx) * gg2 + xx;
    }
    c_last[t] = c;
}

extern "C" void kernel_launch(void* const* d_in, const int* in_sizes, int n_in,
                              void* d_out, int out_size, void* d_ws, size_t ws_size,
                              hipStream_t stream) {
    const float* x    = (const float*)d_in[0];
    const float* c0   = (const float*)d_in[1];
    const float* W    = (const float*)d_in[2];
    const float* bias = (const float*)d_in[3];
    float* out = (float*)d_out;

    char* ws = (char*)d_ws;
    ushort* xb = (ushort*)(ws);                       //  67,108,864 B  (x bf16)
    ushort* WT = (ushort*)(ws + 67108864);            //  25,165,824 B  (W^T bf16, deinterleaved)
    ushort* u0 = (ushort*)(ws + 92274688);            //  67,108,864 B  (u0 bf16)
    ushort* g1 = (ushort*)(ws + 159383552);           //  67,108,864 B
    ushort* g2 = (ushort*)(ws + 226492416);           //  67,108,864 B  -> 293,601,280 total

    hipLaunchKernelGGL(pre_kernel, dim3(5120), dim3(256), 0, stream,
                       (const f32x4*)x, (ushort4v*)xb, W, WT);
    hipLaunchKernelGGL(sru_gemm8, dim3(1536), dim3(512), 0, stream, xb, WT, bias, u0, g1, g2);
    hipLaunchKernelGGL(sru_rec, dim3(512), dim3(64), 0, stream,
                       u0, g1, g2, xb, c0, out, out + (size_t)MROWS * DD);
}

// Round 15
// 570.626 us; speedup vs baseline: 1.6163x; 1.0997x over previous
//
#include <hip/hip_runtime.h>
#include <hip/hip_bf16.h>
#include <cstdint>

#define L_SEQ 1024
#define BSZ   16
#define DIN   2048
#define DD    2048
#define MROWS (L_SEQ * BSZ)   // 16384
#define NCOLS (3 * DD)        // 6144
#define BKT   64              // K per tile
#define NT    (DIN / BKT)     // 32 K-tiles

typedef __attribute__((ext_vector_type(8))) short  short8;
typedef __attribute__((ext_vector_type(4))) float  f32x4;
typedef __attribute__((ext_vector_type(4))) ushort ushort4v;

typedef const __attribute__((address_space(1))) void* gas_ptr;
typedef __attribute__((address_space(3))) void*       las_ptr;

#define GLOAD16(g, l) __builtin_amdgcn_global_load_lds((gas_ptr)(g), (las_ptr)(l), 16, 0, 0)

__device__ __forceinline__ float bf2f(ushort u) {
    return __uint_as_float(((uint32_t)u) << 16);
}
__device__ __forceinline__ ushort f2bf(float f) {
    uint32_t u = __float_as_uint(f);
    uint32_t r = u + 0x7FFFu + ((u >> 16) & 1u);  // RNE
    return (ushort)(r >> 16);
}

// ---------------- K0: fused  x f32->bf16  +  W transpose/deinterleave ----------------
__global__ __launch_bounds__(256) void pre_kernel(const f32x4* __restrict__ x4,
                                                  ushort4v* __restrict__ xb4,
                                                  const float* __restrict__ W,
                                                  ushort* __restrict__ WT) {
    __shared__ float tile[64][65];
    int bid = blockIdx.x;
    if (bid < 2048) {
        int i = bid * 256 + threadIdx.x;
        const int n4 = MROWS * DIN / 4;
        const int stride = 2048 * 256;
        for (; i < n4; i += stride) {
            f32x4 v = x4[i];
            ushort4v o;
            o.x = f2bf(v.x); o.y = f2bf(v.y); o.z = f2bf(v.z); o.w = f2bf(v.w);
            xb4[i] = o;
        }
    } else {
        int b2 = bid - 2048;
        int k0 = (b2 & 31) * 64;
        int n0 = (b2 >> 5) * 64;
        int c  = threadIdx.x & 63;
        int r0 = threadIdx.x >> 6;
#pragma unroll
        for (int rr = 0; rr < 16; ++rr) {
            int r = r0 + rr * 4;
            tile[r][c] = W[(size_t)(k0 + r) * NCOLS + n0 + c];
        }
        __syncthreads();
#pragma unroll
        for (int rr = 0; rr < 16; ++rr) {
            int r = r0 + rr * 4;
            int n = n0 + r;
            int nprime = (n % 3) * DD + (n / 3);
            WT[(size_t)nprime * DIN + k0 + c] = f2bf(tile[c][r]);
        }
    }
}

// ---------------- K1: 256x256 GEMM — ROUND-8/12 SOURCE VERBATIM (best measured: 415 us) ----
#define SLOT(b, s) (&lds8[(((b) << 2) + (s)) * 8192])

#define STAGE_A(b, h, kt) do {                                                   \
    const ushort* _g = Ab + (size_t)((h) * 64 + idx) * DIN + (kt) * BKT + akc;   \
    ushort* _l = SLOT(b, (h)) + tid * 8;                                         \
    GLOAD16(_g, _l);                                                             \
    GLOAD16(_g + (size_t)128 * DIN, _l + 4096);                                  \
} while (0)

#define STAGE_B(b, h2, kt) do {                                                  \
    const ushort* _g0 = Bb + (size_t)(brow0 + (h2) * 32) * DIN + (kt) * BKT + akc;\
    const ushort* _g1 = Bb + (size_t)(brow1 + (h2) * 32) * DIN + (kt) * BKT + akc;\
    ushort* _l = SLOT(b, 2 + (h2)) + tid * 8;                                    \
    GLOAD16(_g0, _l);                                                            \
    GLOAD16(_g1, _l + 4096);                                                     \
} while (0)

#define LD_A2(dst, b, h) do { const ushort* _s = SLOT(b, (h)) + a_rb;            \
    _Pragma("unroll") for (int _m = 0; _m < 4; ++_m) {                           \
        dst[_m][0] = *(const short8*)(_s + _m * 1024 + cs0);                     \
        dst[_m][1] = *(const short8*)(_s + _m * 1024 + cs1); }                   \
} while (0)

#define LD_B(b, h2, bF) do { const ushort* _s = SLOT(b, 2 + (h2)) + b_rb;        \
    _Pragma("unroll") for (int _n = 0; _n < 2; ++_n) {                           \
        bF[_n][0] = *(const short8*)(_s + _n * 1024 + cs0);                      \
        bF[_n][1] = *(const short8*)(_s + _n * 1024 + cs1); }                    \
} while (0)

#define MM(mb, aR, bF, nb) do {                                                  \
    __builtin_amdgcn_s_setprio(1);                                               \
    _Pragma("unroll") for (int _m = 0; _m < 4; ++_m)                             \
    _Pragma("unroll") for (int _n = 0; _n < 2; ++_n) {                           \
        acc[(mb)+_m][(nb)+_n] = __builtin_amdgcn_mfma_f32_16x16x32_bf16(         \
            bF[_n][0], aR[_m][0], acc[(mb)+_m][(nb)+_n], 0, 0, 0);               \
        acc[(mb)+_m][(nb)+_n] = __builtin_amdgcn_mfma_f32_16x16x32_bf16(         \
            bF[_n][1], aR[_m][1], acc[(mb)+_m][(nb)+_n], 0, 0, 0); }             \
    __builtin_amdgcn_s_setprio(0);                                               \
    __builtin_amdgcn_sched_barrier(0);                                           \
} while (0)

#define BARF() do { __builtin_amdgcn_sched_barrier(0);                           \
    __builtin_amdgcn_s_barrier();                                                \
    __builtin_amdgcn_sched_barrier(0); } while (0)

__global__ __launch_bounds__(512, 2) void sru_gemm8(const ushort* __restrict__ A,
                                                    const ushort* __restrict__ Bt,
                                                    const float*  __restrict__ bias,
                                                    ushort* __restrict__ u0,
                                                    ushort* __restrict__ g1,
                                                    ushort* __restrict__ g2) {
    __shared__ alignas(16) ushort lds8[65536];   // 128 KiB

    int bid = blockIdx.x;                        // 1536 blocks (%8==0 -> bijective swizzle)
    int swz = (bid & 7) * 192 + (bid >> 3);
    int bm0 = (swz / 24) * 256;
    int bn0 = (swz % 24) * 256;

    int tid  = threadIdx.x;
    int wave = tid >> 6, lane = tid & 63;
    int wm = wave >> 2, wn = wave & 3;

    int idx    = tid >> 3;
    int schunk = (tid & 7) ^ (idx & 7);
    int akc    = schunk * 8;
    int brow0  = (idx >> 5) * 64 + (idx & 31);
    int brow1  = ((idx >> 5) + 2) * 64 + (idx & 31);
    const ushort* Ab = A  + (size_t)bm0 * DIN;
    const ushort* Bb = Bt + (size_t)bn0 * DIN;

    int lrow = lane & 15, lk = lane >> 4, lx = lane & 7;
    int cs0  = ((0 + lk) ^ lx) * 8;
    int cs1  = ((4 + lk) ^ lx) * 8;
    int a_rb = (wm * 64 + lrow) * 64;
    int b_rb = (wn * 32 + lrow) * 64;

    f32x4 acc[8][4];
    f32x4 zero = {0.f, 0.f, 0.f, 0.f};
#pragma unroll
    for (int i = 0; i < 8; ++i)
#pragma unroll
        for (int j = 0; j < 4; ++j) acc[i][j] = zero;

    STAGE_A(0, 0, 0); STAGE_A(0, 1, 0); STAGE_B(0, 0, 0); STAGE_B(0, 1, 0);
    STAGE_A(1, 0, 1); STAGE_B(1, 0, 1);
    asm volatile("s_waitcnt vmcnt(4)" ::: "memory");
    BARF();

    short8 aFA[4][2], aFB[4][2], bF0[2][2], bF1[2][2];
    LD_A2(aFA, 0, 0);
    __builtin_amdgcn_sched_barrier(0);

    for (int t = 0; t < NT; ++t) {
        int cur = t & 1, nxt = cur ^ 1;
        LD_B(cur, 0, bF0);
        LD_B(cur, 1, bF1);
        STAGE_A(nxt, 1, t + 1);
        BARF(); MM(0, aFA, bF0, 0); BARF();
        LD_A2(aFB, cur, 1);
        STAGE_B(nxt, 1, t + 1);
        BARF(); MM(0, aFA, bF1, 2); BARF();
        STAGE_A(cur, 0, t + 2);
        BARF(); MM(4, aFB, bF0, 0); BARF();
        STAGE_B(cur, 0, t + 2);
        asm volatile("s_waitcnt vmcnt(4)" ::: "memory");
        BARF();
        LD_A2(aFA, nxt, 0);
        MM(4, aFB, bF1, 2);
        BARF();
    }
    asm volatile("s_waitcnt vmcnt(0)" ::: "memory");

    int region = bn0 >> 11;                      // 0:u0 1:g1 2:g2
    int colb = (bn0 & (DD - 1)) + wn * 64 + ((lane >> 4) << 2);
    int rowm = bm0 + wm * 128 + (lane & 15);
    if (region == 0) {
#pragma unroll
        for (int j = 0; j < 4; ++j)
#pragma unroll
            for (int i = 0; i < 4; ++i) {
                f32x4 v = acc[i][j];
                uint32_t lo, hi;
                asm("v_cvt_pk_bf16_f32 %0, %1, %2" : "=v"(lo) : "v"(v[0]), "v"(v[1]));
                asm("v_cvt_pk_bf16_f32 %0, %1, %2" : "=v"(hi) : "v"(v[2]), "v"(v[3]));
                uint2 pk; pk.x = lo; pk.y = hi;
                *(uint2*)&u0[(size_t)(rowm + i * 16) * DD + colb + j * 16] = pk;
                f32x4 w = acc[4 + i][j];
                asm("v_cvt_pk_bf16_f32 %0, %1, %2" : "=v"(lo) : "v"(w[0]), "v"(w[1]));
                asm("v_cvt_pk_bf16_f32 %0, %1, %2" : "=v"(hi) : "v"(w[2]), "v"(w[3]));
                pk.x = lo; pk.y = hi;
                *(uint2*)&u0[(size_t)(rowm + 64 + i * 16) * DD + colb + j * 16] = pk;
            }
    } else {
        const float* bp = bias + (size_t)(region - 1) * DD;
        ushort* gp = (region == 1) ? g1 : g2;
#pragma unroll
        for (int j = 0; j < 4; ++j) {
            float4 bv = *(const float4*)&bp[colb + j * 16];
#pragma unroll
            for (int i = 0; i < 8; ++i) {
                f32x4 v = acc[i][j];
                float s0 = 1.f / (1.f + __expf(-(v[0] + bv.x)));
                float s1 = 1.f / (1.f + __expf(-(v[1] + bv.y)));
                float s2 = 1.f / (1.f + __expf(-(v[2] + bv.z)));
                float s3 = 1.f / (1.f + __expf(-(v[3] + bv.w)));
                uint32_t lo, hi;
                asm("v_cvt_pk_bf16_f32 %0, %1, %2" : "=v"(lo) : "v"(s0), "v"(s1));
                asm("v_cvt_pk_bf16_f32 %0, %1, %2" : "=v"(hi) : "v"(s2), "v"(s3));
                uint2 pk; pk.x = lo; pk.y = hi;
                int rr = rowm + (i >> 2) * 64 + (i & 3) * 16;
                *(uint2*)&gp[(size_t)rr * DD + colb + j * 16] = pk;
            }
        }
    }
}

// ---------------- K2: recurrence — round-8 form, unroll 32 (2x in-flight bytes) ---------
__global__ __launch_bounds__(64) void sru_rec(const ushort* __restrict__ u0,
                                              const ushort* __restrict__ g1,
                                              const ushort* __restrict__ g2,
                                              const ushort* __restrict__ xb,
                                              const float*  __restrict__ c0,
                                              float* __restrict__ h,
                                              float* __restrict__ c_last) {
    int t = blockIdx.x * 64 + threadIdx.x;   // t = b*DD + d
    float c = c0[t];
#pragma unroll 32
    for (int l = 0; l < L_SEQ; ++l) {
        int ix = l * (BSZ * DD) + t;
        float uu  = bf2f(u0[ix]);
        float gg1 = bf2f(g1[ix]);
        float gg2 = bf2f(g2[ix]);
        float xx  = bf2f(xb[ix]);
        c = (c - uu) * gg1 + uu;
        float e  = __expf(-2.f * fabsf(c));
        float th = (1.f - e) / (1.f + e);
        th = copysignf(th, c);
        h[ix] = (th - xx) * gg2 + xx;
    }
    c_last[t] = c;
}

extern "C" void kernel_launch(void* const* d_in, const int* in_sizes, int n_in,
                              void* d_out, int out_size, void* d_ws, size_t ws_size,
                              hipStream_t stream) {
    const float* x    = (const float*)d_in[0];
    const float* c0   = (const float*)d_in[1];
    const float* W    = (const float*)d_in[2];
    const float* bias = (const float*)d_in[3];
    float* out = (float*)d_out;

    char* ws = (char*)d_ws;
    ushort* xb = (ushort*)(ws);                       //  67,108,864 B  (x bf16)
    ushort* WT = (ushort*)(ws + 67108864);            //  25,165,824 B  (W^T bf16, deinterleaved)
    ushort* u0 = (ushort*)(ws + 92274688);            //  67,108,864 B  (u0 bf16)
    ushort* g1 = (ushort*)(ws + 159383552);           //  67,108,864 B
    ushort* g2 = (ushort*)(ws + 226492416);           //  67,108,864 B  -> 293,601,280 total

    hipLaunchKernelGGL(pre_kernel, dim3(5120), dim3(256), 0, stream,
                       (const f32x4*)x, (ushort4v*)xb, W, WT);
    hipLaunchKernelGGL(sru_gemm8, dim3(1536), dim3(512), 0, stream, xb, WT, bias, u0, g1, g2);
    hipLaunchKernelGGL(sru_rec, dim3(512), dim3(64), 0, stream,
                       u0, g1, g2, xb, c0, out, out + (size_t)MROWS * DD);
}

// Round 16
// 564.269 us; speedup vs baseline: 1.6345x; 1.0113x over previous
//
#include <hip/hip_runtime.h>
#include <hip/hip_bf16.h>
#include <cstdint>

#define L_SEQ 1024
#define BSZ   16
#define DIN   2048
#define DD    2048
#define MROWS (L_SEQ * BSZ)   // 16384
#define NCOLS (3 * DD)        // 6144
#define BKT   64              // K per tile
#define NT    (DIN / BKT)     // 32 K-tiles

typedef __attribute__((ext_vector_type(8))) short  short8;
typedef __attribute__((ext_vector_type(4))) float  f32x4;
typedef __attribute__((ext_vector_type(4))) ushort ushort4v;

typedef const __attribute__((address_space(1))) void* gas_ptr;
typedef __attribute__((address_space(3))) void*       las_ptr;

#define GLOAD16(g, l) __builtin_amdgcn_global_load_lds((gas_ptr)(g), (las_ptr)(l), 16, 0, 0)

__device__ __forceinline__ float bf2f(ushort u) {
    return __uint_as_float(((uint32_t)u) << 16);
}
__device__ __forceinline__ ushort f2bf(float f) {
    uint32_t u = __float_as_uint(f);
    uint32_t r = u + 0x7FFFu + ((u >> 16) & 1u);  // RNE
    return (ushort)(r >> 16);
}

// ---------------- K0: fused  x f32->bf16  +  W transpose/deinterleave ----------------
__global__ __launch_bounds__(256) void pre_kernel(const f32x4* __restrict__ x4,
                                                  ushort4v* __restrict__ xb4,
                                                  const float* __restrict__ W,
                                                  ushort* __restrict__ WT) {
    __shared__ float tile[64][65];
    int bid = blockIdx.x;
    if (bid < 2048) {
        int i = bid * 256 + threadIdx.x;
        const int n4 = MROWS * DIN / 4;
        const int stride = 2048 * 256;
        for (; i < n4; i += stride) {
            f32x4 v = x4[i];
            ushort4v o;
            o.x = f2bf(v.x); o.y = f2bf(v.y); o.z = f2bf(v.z); o.w = f2bf(v.w);
            xb4[i] = o;
        }
    } else {
        int b2 = bid - 2048;
        int k0 = (b2 & 31) * 64;
        int n0 = (b2 >> 5) * 64;
        int c  = threadIdx.x & 63;
        int r0 = threadIdx.x >> 6;
#pragma unroll
        for (int rr = 0; rr < 16; ++rr) {
            int r = r0 + rr * 4;
            tile[r][c] = W[(size_t)(k0 + r) * NCOLS + n0 + c];
        }
        __syncthreads();
#pragma unroll
        for (int rr = 0; rr < 16; ++rr) {
            int r = r0 + rr * 4;
            int n = n0 + r;
            int nprime = (n % 3) * DD + (n / 3);
            WT[(size_t)nprime * DIN + k0 + c] = f2bf(tile[c][r]);
        }
    }
}

// ---------------- K1: 256x256 GEMM — r8 schedule + supertile swizzle + full read-ahead ----
#define SLOT(b, s) (&lds8[(((b) << 2) + (s)) * 8192])

#define STAGE_A(b, h, kt) do {                                                   \
    const ushort* _g = Ab + (size_t)((h) * 64 + idx) * DIN + (kt) * BKT + akc;   \
    ushort* _l = SLOT(b, (h)) + tid * 8;                                         \
    GLOAD16(_g, _l);                                                             \
    GLOAD16(_g + (size_t)128 * DIN, _l + 4096);                                  \
} while (0)

#define STAGE_B(b, h2, kt) do {                                                  \
    const ushort* _g0 = Bb + (size_t)(brow0 + (h2) * 32) * DIN + (kt) * BKT + akc;\
    const ushort* _g1 = Bb + (size_t)(brow1 + (h2) * 32) * DIN + (kt) * BKT + akc;\
    ushort* _l = SLOT(b, 2 + (h2)) + tid * 8;                                    \
    GLOAD16(_g0, _l);                                                            \
    GLOAD16(_g1, _l + 4096);                                                     \
} while (0)

#define LD_A2(dst, b, h) do { const ushort* _s = SLOT(b, (h)) + a_rb;            \
    _Pragma("unroll") for (int _m = 0; _m < 4; ++_m) {                           \
        dst[_m][0] = *(const short8*)(_s + _m * 1024 + cs0);                     \
        dst[_m][1] = *(const short8*)(_s + _m * 1024 + cs1); }                   \
} while (0)

#define LD_B(b, h2, bF) do { const ushort* _s = SLOT(b, 2 + (h2)) + b_rb;        \
    _Pragma("unroll") for (int _n = 0; _n < 2; ++_n) {                           \
        bF[_n][0] = *(const short8*)(_s + _n * 1024 + cs0);                      \
        bF[_n][1] = *(const short8*)(_s + _n * 1024 + cs1); }                    \
} while (0)

#define MM(mb, aR, bF, nb) do {                                                  \
    __builtin_amdgcn_s_setprio(1);                                               \
    _Pragma("unroll") for (int _m = 0; _m < 4; ++_m)                             \
    _Pragma("unroll") for (int _n = 0; _n < 2; ++_n) {                           \
        acc[(mb)+_m][(nb)+_n] = __builtin_amdgcn_mfma_f32_16x16x32_bf16(         \
            bF[_n][0], aR[_m][0], acc[(mb)+_m][(nb)+_n], 0, 0, 0);               \
        acc[(mb)+_m][(nb)+_n] = __builtin_amdgcn_mfma_f32_16x16x32_bf16(         \
            bF[_n][1], aR[_m][1], acc[(mb)+_m][(nb)+_n], 0, 0, 0); }             \
    __builtin_amdgcn_s_setprio(0);                                               \
    __builtin_amdgcn_sched_barrier(0);                                           \
} while (0)

#define BARF() do { __builtin_amdgcn_sched_barrier(0);                           \
    __builtin_amdgcn_s_barrier();                                                \
    __builtin_amdgcn_sched_barrier(0); } while (0)

__global__ __launch_bounds__(512, 2) void sru_gemm8(const ushort* __restrict__ A,
                                                    const ushort* __restrict__ Bt,
                                                    const float*  __restrict__ bias,
                                                    ushort* __restrict__ u0,
                                                    ushort* __restrict__ g1,
                                                    ushort* __restrict__ g2) {
    __shared__ alignas(16) ushort lds8[65536];   // 128 KiB

    // supertile swizzle: per XCD (192 blocks), 4bm x 4bn supertiles so the ~32
    // concurrent blocks share ~8 panels (L2-resident) instead of 2+24.
    int bid = blockIdx.x;
    int xcd = bid & 7, local = bid >> 3;         // local in [0,192)
    int st = local >> 4, wi = local & 15;        // 12 supertiles of 16
    int bm0 = (xcd * 8 + (st & 1) * 4 + (wi & 3)) * 256;
    int bn0 = ((st >> 1) * 4 + (wi >> 2)) * 256;

    int tid  = threadIdx.x;
    int wave = tid >> 6, lane = tid & 63;
    int wm = wave >> 2, wn = wave & 3;

    int idx    = tid >> 3;
    int schunk = (tid & 7) ^ (idx & 7);
    int akc    = schunk * 8;
    int brow0  = (idx >> 5) * 64 + (idx & 31);
    int brow1  = ((idx >> 5) + 2) * 64 + (idx & 31);
    const ushort* Ab = A  + (size_t)bm0 * DIN;
    const ushort* Bb = Bt + (size_t)bn0 * DIN;

    int lrow = lane & 15, lk = lane >> 4, lx = lane & 7;
    int cs0  = ((0 + lk) ^ lx) * 8;
    int cs1  = ((4 + lk) ^ lx) * 8;
    int a_rb = (wm * 64 + lrow) * 64;
    int b_rb = (wn * 32 + lrow) * 64;

    f32x4 acc[8][4];
    f32x4 zero = {0.f, 0.f, 0.f, 0.f};
#pragma unroll
    for (int i = 0; i < 8; ++i)
#pragma unroll
        for (int j = 0; j < 4; ++j) acc[i][j] = zero;

    STAGE_A(0, 0, 0); STAGE_A(0, 1, 0); STAGE_B(0, 0, 0); STAGE_B(0, 1, 0);
    STAGE_A(1, 0, 1); STAGE_B(1, 0, 1);
    asm volatile("s_waitcnt vmcnt(4)" ::: "memory");
    BARF();

    short8 aFA[4][2], aFB[4][2], bF0[2][2], bF1[2][2];
    LD_A2(aFA, 0, 0);
    LD_B(0, 0, bF0);                             // tile0 B0 pre-read (full read-ahead)
    __builtin_amdgcn_sched_barrier(0);

    for (int t = 0; t < NT; ++t) {
        int cur = t & 1, nxt = cur ^ 1;
        // ph0: bF1 read-ahead (used ph1); MM(A0xB0) uses pre-read aFA,bF0
        LD_B(cur, 1, bF1);
        STAGE_A(nxt, 1, t + 1);
        BARF(); MM(0, aFA, bF0, 0); BARF();
        // ph1: aFB read-ahead (used ph2/ph3); MM(A0xB1)
        LD_A2(aFB, cur, 1);
        STAGE_B(nxt, 1, t + 1);
        BARF(); MM(0, aFA, bF1, 2); BARF();
        // ph2: no reads; MM(A1xB0)
        STAGE_A(cur, 0, t + 2);
        BARF(); MM(4, aFB, bF0, 0); BARF();
        // ph3: vmcnt(4) proves tile t+1 landed; read its A0+B0 (next ph0 operands); MM(A1xB1)
        STAGE_B(cur, 0, t + 2);
        asm volatile("s_waitcnt vmcnt(4)" ::: "memory");
        BARF();
        LD_A2(aFA, nxt, 0);
        LD_B(nxt, 0, bF0);
        __builtin_amdgcn_sched_barrier(0);
        MM(4, aFB, bF1, 2);
        BARF();
    }
    asm volatile("s_waitcnt vmcnt(0)" ::: "memory");

    int region = bn0 >> 11;                      // 0:u0 1:g1 2:g2
    int colb = (bn0 & (DD - 1)) + wn * 64 + ((lane >> 4) << 2);
    int rowm = bm0 + wm * 128 + (lane & 15);
    if (region == 0) {
#pragma unroll
        for (int j = 0; j < 4; ++j)
#pragma unroll
            for (int i = 0; i < 4; ++i) {
                f32x4 v = acc[i][j];
                uint32_t lo, hi;
                asm("v_cvt_pk_bf16_f32 %0, %1, %2" : "=v"(lo) : "v"(v[0]), "v"(v[1]));
                asm("v_cvt_pk_bf16_f32 %0, %1, %2" : "=v"(hi) : "v"(v[2]), "v"(v[3]));
                uint2 pk; pk.x = lo; pk.y = hi;
                *(uint2*)&u0[(size_t)(rowm + i * 16) * DD + colb + j * 16] = pk;
                f32x4 w = acc[4 + i][j];
                asm("v_cvt_pk_bf16_f32 %0, %1, %2" : "=v"(lo) : "v"(w[0]), "v"(w[1]));
                asm("v_cvt_pk_bf16_f32 %0, %1, %2" : "=v"(hi) : "v"(w[2]), "v"(w[3]));
                pk.x = lo; pk.y = hi;
                *(uint2*)&u0[(size_t)(rowm + 64 + i * 16) * DD + colb + j * 16] = pk;
            }
    } else {
        const float* bp = bias + (size_t)(region - 1) * DD;
        ushort* gp = (region == 1) ? g1 : g2;
#pragma unroll
        for (int j = 0; j < 4; ++j) {
            float4 bv = *(const float4*)&bp[colb + j * 16];
#pragma unroll
            for (int i = 0; i < 8; ++i) {
                f32x4 v = acc[i][j];
                float s0 = 1.f / (1.f + __expf(-(v[0] + bv.x)));
                float s1 = 1.f / (1.f + __expf(-(v[1] + bv.y)));
                float s2 = 1.f / (1.f + __expf(-(v[2] + bv.z)));
                float s3 = 1.f / (1.f + __expf(-(v[3] + bv.w)));
                uint32_t lo, hi;
                asm("v_cvt_pk_bf16_f32 %0, %1, %2" : "=v"(lo) : "v"(s0), "v"(s1));
                asm("v_cvt_pk_bf16_f32 %0, %1, %2" : "=v"(hi) : "v"(s2), "v"(s3));
                uint2 pk; pk.x = lo; pk.y = hi;
                int rr = rowm + (i >> 2) * 64 + (i & 3) * 16;
                *(uint2*)&gp[(size_t)rr * DD + colb + j * 16] = pk;
            }
        }
    }
}

// ---------------- K2: recurrence — round-8 form, unroll 32 ------------------------------
__global__ __launch_bounds__(64) void sru_rec(const ushort* __restrict__ u0,
                                              const ushort* __restrict__ g1,
                                              const ushort* __restrict__ g2,
                                              const ushort* __restrict__ xb,
                                              const float*  __restrict__ c0,
                                              float* __restrict__ h,
                                              float* __restrict__ c_last) {
    int t = blockIdx.x * 64 + threadIdx.x;   // t = b*DD + d
    float c = c0[t];
#pragma unroll 32
    for (int l = 0; l < L_SEQ; ++l) {
        int ix = l * (BSZ * DD) + t;
        float uu  = bf2f(u0[ix]);
        float gg1 = bf2f(g1[ix]);
        float gg2 = bf2f(g2[ix]);
        float xx  = bf2f(xb[ix]);
        c = (c - uu) * gg1 + uu;
        float e  = __expf(-2.f * fabsf(c));
        float th = (1.f - e) / (1.f + e);
        th = copysignf(th, c);
        h[ix] = (th - xx) * gg2 + xx;
    }
    c_last[t] = c;
}

extern "C" void kernel_launch(void* const* d_in, const int* in_sizes, int n_in,
                              void* d_out, int out_size, void* d_ws, size_t ws_size,
                              hipStream_t stream) {
    const float* x    = (const float*)d_in[0];
    const float* c0   = (const float*)d_in[1];
    const float* W    = (const float*)d_in[2];
    const float* bias = (const float*)d_in[3];
    float* out = (float*)d_out;

    char* ws = (char*)d_ws;
    ushort* xb = (ushort*)(ws);                       //  67,108,864 B  (x bf16)
    ushort* WT = (ushort*)(ws + 67108864);            //  25,165,824 B  (W^T bf16, deinterleaved)
    ushort* u0 = (ushort*)(ws + 92274688);            //  67,108,864 B  (u0 bf16)
    ushort* g1 = (ushort*)(ws + 159383552);           //  67,108,864 B
    ushort* g2 = (ushort*)(ws + 226492416);           //  67,108,864 B  -> 293,601,280 total

    hipLaunchKernelGGL(pre_kernel, dim3(5120), dim3(256), 0, stream,
                       (const f32x4*)x, (ushort4v*)xb, W, WT);
    hipLaunchKernelGGL(sru_gemm8, dim3(1536), dim3(512), 0, stream, xb, WT, bias, u0, g1, g2);
    hipLaunchKernelGGL(sru_rec, dim3(512), dim3(64), 0, stream,
                       u0, g1, g2, xb, c0, out, out + (size_t)MROWS * DD);
}

// Round 17
// 550.492 us; speedup vs baseline: 1.6754x; 1.0250x over previous
//
#include <hip/hip_runtime.h>
#include <hip/hip_bf16.h>
#include <cstdint>

#define L_SEQ 1024
#define BSZ   16
#define DIN   2048
#define DD    2048
#define MROWS (L_SEQ * BSZ)   // 16384
#define NCOLS (3 * DD)        // 6144
#define BKT   64              // K per tile
#define NT    (DIN / BKT)     // 32 K-tiles

typedef __attribute__((ext_vector_type(8))) short  short8;
typedef __attribute__((ext_vector_type(4))) float  f32x4;
typedef __attribute__((ext_vector_type(4))) ushort ushort4v;

typedef const __attribute__((address_space(1))) void* gas_ptr;
typedef __attribute__((address_space(3))) void*       las_ptr;

#define GLOAD16(g, l) __builtin_amdgcn_global_load_lds((gas_ptr)(g), (las_ptr)(l), 16, 0, 0)

__device__ __forceinline__ float bf2f(ushort u) {
    return __uint_as_float(((uint32_t)u) << 16);
}
__device__ __forceinline__ ushort f2bf(float f) {
    uint32_t u = __float_as_uint(f);
    uint32_t r = u + 0x7FFFu + ((u >> 16) & 1u);  // RNE
    return (ushort)(r >> 16);
}

// ---------------- K0: fused  x f32->bf16  +  W transpose/deinterleave ----------------
__global__ __launch_bounds__(256) void pre_kernel(const f32x4* __restrict__ x4,
                                                  ushort4v* __restrict__ xb4,
                                                  const float* __restrict__ W,
                                                  ushort* __restrict__ WT) {
    __shared__ float tile[64][65];
    int bid = blockIdx.x;
    if (bid < 2048) {
        int i = bid * 256 + threadIdx.x;
        const int n4 = MROWS * DIN / 4;
        const int stride = 2048 * 256;
        for (; i < n4; i += stride) {
            f32x4 v = x4[i];
            ushort4v o;
            o.x = f2bf(v.x); o.y = f2bf(v.y); o.z = f2bf(v.z); o.w = f2bf(v.w);
            xb4[i] = o;
        }
    } else {
        int b2 = bid - 2048;
        int k0 = (b2 & 31) * 64;
        int n0 = (b2 >> 5) * 64;
        int c  = threadIdx.x & 63;
        int r0 = threadIdx.x >> 6;
#pragma unroll
        for (int rr = 0; rr < 16; ++rr) {
            int r = r0 + rr * 4;
            tile[r][c] = W[(size_t)(k0 + r) * NCOLS + n0 + c];
        }
        __syncthreads();
#pragma unroll
        for (int rr = 0; rr < 16; ++rr) {
            int r = r0 + rr * 4;
            int n = n0 + r;
            int nprime = (n % 3) * DD + (n / 3);
            WT[(size_t)nprime * DIN + k0 + c] = f2bf(tile[c][r]);
        }
    }
}

// ---------------- K1: 256x256 GEMM — r16 + SINGLE barrier per phase (ledger-verified) ----
// Per phase: [LD; STAGE; BAR; MM]. Safety: passing BAR(p) proves all waves completed
// MM(p-1), which lgkm-drained the LDS reads of every slot that phase p's STAGE
// overwrites (reads are issued >=2 phases before their slot's overwrite). vmcnt(4)
// once per tile at ph3 + that phase's BAR still publish tile t+1's slots before
// ph3's LD(nxt) reads them.
#define SLOT(b, s) (&lds8[(((b) << 2) + (s)) * 8192])

#define STAGE_A(b, h, kt) do {                                                   \
    const ushort* _g = Ab + (size_t)((h) * 64 + idx) * DIN + (kt) * BKT + akc;   \
    ushort* _l = SLOT(b, (h)) + tid * 8;                                         \
    GLOAD16(_g, _l);                                                             \
    GLOAD16(_g + (size_t)128 * DIN, _l + 4096);                                  \
} while (0)

#define STAGE_B(b, h2, kt) do {                                                  \
    const ushort* _g0 = Bb + (size_t)(brow0 + (h2) * 32) * DIN + (kt) * BKT + akc;\
    const ushort* _g1 = Bb + (size_t)(brow1 + (h2) * 32) * DIN + (kt) * BKT + akc;\
    ushort* _l = SLOT(b, 2 + (h2)) + tid * 8;                                    \
    GLOAD16(_g0, _l);                                                            \
    GLOAD16(_g1, _l + 4096);                                                     \
} while (0)

#define LD_A2(dst, b, h) do { const ushort* _s = SLOT(b, (h)) + a_rb;            \
    _Pragma("unroll") for (int _m = 0; _m < 4; ++_m) {                           \
        dst[_m][0] = *(const short8*)(_s + _m * 1024 + cs0);                     \
        dst[_m][1] = *(const short8*)(_s + _m * 1024 + cs1); }                   \
} while (0)

#define LD_B(b, h2, bF) do { const ushort* _s = SLOT(b, 2 + (h2)) + b_rb;        \
    _Pragma("unroll") for (int _n = 0; _n < 2; ++_n) {                           \
        bF[_n][0] = *(const short8*)(_s + _n * 1024 + cs0);                      \
        bF[_n][1] = *(const short8*)(_s + _n * 1024 + cs1); }                    \
} while (0)

#define MM(mb, aR, bF, nb) do {                                                  \
    __builtin_amdgcn_s_setprio(1);                                               \
    _Pragma("unroll") for (int _m = 0; _m < 4; ++_m)                             \
    _Pragma("unroll") for (int _n = 0; _n < 2; ++_n) {                           \
        acc[(mb)+_m][(nb)+_n] = __builtin_amdgcn_mfma_f32_16x16x32_bf16(         \
            bF[_n][0], aR[_m][0], acc[(mb)+_m][(nb)+_n], 0, 0, 0);               \
        acc[(mb)+_m][(nb)+_n] = __builtin_amdgcn_mfma_f32_16x16x32_bf16(         \
            bF[_n][1], aR[_m][1], acc[(mb)+_m][(nb)+_n], 0, 0, 0); }             \
    __builtin_amdgcn_s_setprio(0);                                               \
    __builtin_amdgcn_sched_barrier(0);                                           \
} while (0)

#define BARF() do { __builtin_amdgcn_sched_barrier(0);                           \
    __builtin_amdgcn_s_barrier();                                                \
    __builtin_amdgcn_sched_barrier(0); } while (0)

__global__ __launch_bounds__(512, 2) void sru_gemm8(const ushort* __restrict__ A,
                                                    const ushort* __restrict__ Bt,
                                                    const float*  __restrict__ bias,
                                                    ushort* __restrict__ u0,
                                                    ushort* __restrict__ g1,
                                                    ushort* __restrict__ g2) {
    __shared__ alignas(16) ushort lds8[65536];   // 128 KiB

    // supertile swizzle: per XCD (192 blocks), 4bm x 4bn supertiles so the ~32
    // concurrent blocks share ~8 panels (L2-resident) instead of 2+24.
    int bid = blockIdx.x;
    int xcd = bid & 7, local = bid >> 3;         // local in [0,192)
    int st = local >> 4, wi = local & 15;        // 12 supertiles of 16
    int bm0 = (xcd * 8 + (st & 1) * 4 + (wi & 3)) * 256;
    int bn0 = ((st >> 1) * 4 + (wi >> 2)) * 256;

    int tid  = threadIdx.x;
    int wave = tid >> 6, lane = tid & 63;
    int wm = wave >> 2, wn = wave & 3;

    int idx    = tid >> 3;
    int schunk = (tid & 7) ^ (idx & 7);
    int akc    = schunk * 8;
    int brow0  = (idx >> 5) * 64 + (idx & 31);
    int brow1  = ((idx >> 5) + 2) * 64 + (idx & 31);
    const ushort* Ab = A  + (size_t)bm0 * DIN;
    const ushort* Bb = Bt + (size_t)bn0 * DIN;

    int lrow = lane & 15, lk = lane >> 4, lx = lane & 7;
    int cs0  = ((0 + lk) ^ lx) * 8;
    int cs1  = ((4 + lk) ^ lx) * 8;
    int a_rb = (wm * 64 + lrow) * 64;
    int b_rb = (wn * 32 + lrow) * 64;

    f32x4 acc[8][4];
    f32x4 zero = {0.f, 0.f, 0.f, 0.f};
#pragma unroll
    for (int i = 0; i < 8; ++i)
#pragma unroll
        for (int j = 0; j < 4; ++j) acc[i][j] = zero;

    STAGE_A(0, 0, 0); STAGE_A(0, 1, 0); STAGE_B(0, 0, 0); STAGE_B(0, 1, 0);
    STAGE_A(1, 0, 1); STAGE_B(1, 0, 1);
    asm volatile("s_waitcnt vmcnt(4)" ::: "memory");
    BARF();

    short8 aFA[4][2], aFB[4][2], bF0[2][2], bF1[2][2];
    LD_A2(aFA, 0, 0);
    LD_B(0, 0, bF0);                             // tile0 B0 pre-read
    __builtin_amdgcn_sched_barrier(0);

    for (int t = 0; t < NT; ++t) {
        int cur = t & 1, nxt = cur ^ 1;
        // ph0: bF1 read-ahead; MM(A0xB0) on pre-read aFA,bF0
        LD_B(cur, 1, bF1);
        STAGE_A(nxt, 1, t + 1);
        BARF(); MM(0, aFA, bF0, 0);
        // ph1: aFB read-ahead; MM(A0xB1)
        LD_A2(aFB, cur, 1);
        STAGE_B(nxt, 1, t + 1);
        BARF(); MM(0, aFA, bF1, 2);
        // ph2: MM(A1xB0)
        STAGE_A(cur, 0, t + 2);
        BARF(); MM(4, aFB, bF0, 0);
        // ph3: vmcnt(4) proves tile t+1 landed; BAR publishes; read its A0+B0; MM(A1xB1)
        STAGE_B(cur, 0, t + 2);
        asm volatile("s_waitcnt vmcnt(4)" ::: "memory");
        BARF();
        LD_A2(aFA, nxt, 0);
        LD_B(nxt, 0, bF0);
        __builtin_amdgcn_sched_barrier(0);
        MM(4, aFB, bF1, 2);
    }
    asm volatile("s_waitcnt vmcnt(0)" ::: "memory");

    int region = bn0 >> 11;                      // 0:u0 1:g1 2:g2
    int colb = (bn0 & (DD - 1)) + wn * 64 + ((lane >> 4) << 2);
    int rowm = bm0 + wm * 128 + (lane & 15);
    if (region == 0) {
#pragma unroll
        for (int j = 0; j < 4; ++j)
#pragma unroll
            for (int i = 0; i < 4; ++i) {
                f32x4 v = acc[i][j];
                uint32_t lo, hi;
                asm("v_cvt_pk_bf16_f32 %0, %1, %2" : "=v"(lo) : "v"(v[0]), "v"(v[1]));
                asm("v_cvt_pk_bf16_f32 %0, %1, %2" : "=v"(hi) : "v"(v[2]), "v"(v[3]));
                uint2 pk; pk.x = lo; pk.y = hi;
                *(uint2*)&u0[(size_t)(rowm + i * 16) * DD + colb + j * 16] = pk;
                f32x4 w = acc[4 + i][j];
                asm("v_cvt_pk_bf16_f32 %0, %1, %2" : "=v"(lo) : "v"(w[0]), "v"(w[1]));
                asm("v_cvt_pk_bf16_f32 %0, %1, %2" : "=v"(hi) : "v"(w[2]), "v"(w[3]));
                pk.x = lo; pk.y = hi;
                *(uint2*)&u0[(size_t)(rowm + 64 + i * 16) * DD + colb + j * 16] = pk;
            }
    } else {
        const float* bp = bias + (size_t)(region - 1) * DD;
        ushort* gp = (region == 1) ? g1 : g2;
#pragma unroll
        for (int j = 0; j < 4; ++j) {
            float4 bv = *(const float4*)&bp[colb + j * 16];
#pragma unroll
            for (int i = 0; i < 8; ++i) {
                f32x4 v = acc[i][j];
                float s0 = 1.f / (1.f + __expf(-(v[0] + bv.x)));
                float s1 = 1.f / (1.f + __expf(-(v[1] + bv.y)));
                float s2 = 1.f / (1.f + __expf(-(v[2] + bv.z)));
                float s3 = 1.f / (1.f + __expf(-(v[3] + bv.w)));
                uint32_t lo, hi;
                asm("v_cvt_pk_bf16_f32 %0, %1, %2" : "=v"(lo) : "v"(s0), "v"(s1));
                asm("v_cvt_pk_bf16_f32 %0, %1, %2" : "=v"(hi) : "v"(s2), "v"(s3));
                uint2 pk; pk.x = lo; pk.y = hi;
                int rr = rowm + (i >> 2) * 64 + (i & 3) * 16;
                *(uint2*)&gp[(size_t)rr * DD + colb + j * 16] = pk;
            }
        }
    }
}

// ---------------- K2: recurrence — round-8 form, unroll 32 ------------------------------
__global__ __launch_bounds__(64) void sru_rec(const ushort* __restrict__ u0,
                                              const ushort* __restrict__ g1,
                                              const ushort* __restrict__ g2,
                                              const ushort* __restrict__ xb,
                                              const float*  __restrict__ c0,
                                              float* __restrict__ h,
                                              float* __restrict__ c_last) {
    int t = blockIdx.x * 64 + threadIdx.x;   // t = b*DD + d
    float c = c0[t];
#pragma unroll 32
    for (int l = 0; l < L_SEQ; ++l) {
        int ix = l * (BSZ * DD) + t;
        float uu  = bf2f(u0[ix]);
        float gg1 = bf2f(g1[ix]);
        float gg2 = bf2f(g2[ix]);
        float xx  = bf2f(xb[ix]);
        c = (c - uu) * gg1 + uu;
        float e  = __expf(-2.f * fabsf(c));
        float th = (1.f - e) / (1.f + e);
        th = copysignf(th, c);
        h[ix] = (th - xx) * gg2 + xx;
    }
    c_last[t] = c;
}

extern "C" void kernel_launch(void* const* d_in, const int* in_sizes, int n_in,
                              void* d_out, int out_size, void* d_ws, size_t ws_size,
                              hipStream_t stream) {
    const float* x    = (const float*)d_in[0];
    const float* c0   = (const float*)d_in[1];
    const float* W    = (const float*)d_in[2];
    const float* bias = (const float*)d_in[3];
    float* out = (float*)d_out;

    char* ws = (char*)d_ws;
    ushort* xb = (ushort*)(ws);                       //  67,108,864 B  (x bf16)
    ushort* WT = (ushort*)(ws + 67108864);            //  25,165,824 B  (W^T bf16, deinterleaved)
    ushort* u0 = (ushort*)(ws + 92274688);            //  67,108,864 B  (u0 bf16)
    ushort* g1 = (ushort*)(ws + 159383552);           //  67,108,864 B
    ushort* g2 = (ushort*)(ws + 226492416);           //  67,108,864 B  -> 293,601,280 total

    hipLaunchKernelGGL(pre_kernel, dim3(5120), dim3(256), 0, stream,
                       (const f32x4*)x, (ushort4v*)xb, W, WT);
    hipLaunchKernelGGL(sru_gemm8, dim3(1536), dim3(512), 0, stream, xb, WT, bias, u0, g1, g2);
    hipLaunchKernelGGL(sru_rec, dim3(512), dim3(64), 0, stream,
                       u0, g1, g2, xb, c0, out, out + (size_t)MROWS * DD);
}

// Round 18
// 547.297 us; speedup vs baseline: 1.6851x; 1.0058x over previous
//
#include <hip/hip_runtime.h>
#include <hip/hip_bf16.h>
#include <cstdint>

#define L_SEQ 1024
#define BSZ   16
#define DIN   2048
#define DD    2048
#define MROWS (L_SEQ * BSZ)   // 16384
#define NCOLS (3 * DD)        // 6144
#define BKT   64              // K per tile
#define NT    (DIN / BKT)     // 32 K-tiles

typedef __attribute__((ext_vector_type(8))) short  short8;
typedef __attribute__((ext_vector_type(4))) float  f32x4;
typedef __attribute__((ext_vector_type(4))) ushort ushort4v;

typedef const __attribute__((address_space(1))) void* gas_ptr;
typedef __attribute__((address_space(3))) void*       las_ptr;

#define GLOAD16(g, l) __builtin_amdgcn_global_load_lds((gas_ptr)(g), (las_ptr)(l), 16, 0, 0)

__device__ __forceinline__ float bf2f(ushort u) {
    return __uint_as_float(((uint32_t)u) << 16);
}
__device__ __forceinline__ ushort f2bf(float f) {
    uint32_t u = __float_as_uint(f);
    uint32_t r = u + 0x7FFFu + ((u >> 16) & 1u);  // RNE
    return (ushort)(r >> 16);
}

// ---------------- K0: fused  x f32->bf16  +  W transpose/deinterleave ----------------
__global__ __launch_bounds__(256) void pre_kernel(const f32x4* __restrict__ x4,
                                                  ushort4v* __restrict__ xb4,
                                                  const float* __restrict__ W,
                                                  ushort* __restrict__ WT) {
    __shared__ float tile[64][65];
    int bid = blockIdx.x;
    if (bid < 2048) {
        int i = bid * 256 + threadIdx.x;
        const int n4 = MROWS * DIN / 4;
        const int stride = 2048 * 256;
        for (; i < n4; i += stride) {
            f32x4 v = x4[i];
            ushort4v o;
            o.x = f2bf(v.x); o.y = f2bf(v.y); o.z = f2bf(v.z); o.w = f2bf(v.w);
            xb4[i] = o;
        }
    } else {
        int b2 = bid - 2048;
        int k0 = (b2 & 31) * 64;
        int n0 = (b2 >> 5) * 64;
        int c  = threadIdx.x & 63;
        int r0 = threadIdx.x >> 6;
#pragma unroll
        for (int rr = 0; rr < 16; ++rr) {
            int r = r0 + rr * 4;
            tile[r][c] = W[(size_t)(k0 + r) * NCOLS + n0 + c];
        }
        __syncthreads();
#pragma unroll
        for (int rr = 0; rr < 16; ++rr) {
            int r = r0 + rr * 4;
            int n = n0 + r;
            int nprime = (n % 3) * DD + (n / 3);
            WT[(size_t)nprime * DIN + k0 + c] = f2bf(tile[c][r]);
        }
    }
}

// ---------------- K1: 256x256 GEMM — TWO barriers per K-tile (ledger-verified) ----------
// P0: [LD aFB,bF1; BAR; MM(A0xB0); MM(A0xB1)]
// P1: [vmcnt(0); BAR; STAGE tile t+2 (all 4 slots, into cur); LD aFA(nxt);
//      MM(A1xB0); MM(A1xB1); LD bF0(nxt)]
// WAR: stages sit after BAR(P1,t); all reads of cur's slots are consumed by MM(P0,t),
// which precedes BAR(P1,t) in program order -> passage proves drain. RAW: tile t+1's
// 8 stage-instrs (issued P1(t-1) post-BAR) are drained by vmcnt(0) and published by
// BAR before any read of them. In-order lgkm: aFB read before bF1 so MM(P0)'s bF1
// wait covers aFB.
#define SLOT(b, s) (&lds8[(((b) << 2) + (s)) * 8192])

#define STAGE_A(b, h, kt) do {                                                   \
    const ushort* _g = Ab + (size_t)((h) * 64 + idx) * DIN + (kt) * BKT + akc;   \
    ushort* _l = SLOT(b, (h)) + tid * 8;                                         \
    GLOAD16(_g, _l);                                                             \
    GLOAD16(_g + (size_t)128 * DIN, _l + 4096);                                  \
} while (0)

#define STAGE_B(b, h2, kt) do {                                                  \
    const ushort* _g0 = Bb + (size_t)(brow0 + (h2) * 32) * DIN + (kt) * BKT + akc;\
    const ushort* _g1 = Bb + (size_t)(brow1 + (h2) * 32) * DIN + (kt) * BKT + akc;\
    ushort* _l = SLOT(b, 2 + (h2)) + tid * 8;                                    \
    GLOAD16(_g0, _l);                                                            \
    GLOAD16(_g1, _l + 4096);                                                     \
} while (0)

#define LD_A2(dst, b, h) do { const ushort* _s = SLOT(b, (h)) + a_rb;            \
    _Pragma("unroll") for (int _m = 0; _m < 4; ++_m) {                           \
        dst[_m][0] = *(const short8*)(_s + _m * 1024 + cs0);                     \
        dst[_m][1] = *(const short8*)(_s + _m * 1024 + cs1); }                   \
} while (0)

#define LD_B(b, h2, bF) do { const ushort* _s = SLOT(b, 2 + (h2)) + b_rb;        \
    _Pragma("unroll") for (int _n = 0; _n < 2; ++_n) {                           \
        bF[_n][0] = *(const short8*)(_s + _n * 1024 + cs0);                      \
        bF[_n][1] = *(const short8*)(_s + _n * 1024 + cs1); }                    \
} while (0)

#define MM(mb, aR, bF, nb) do {                                                  \
    __builtin_amdgcn_s_setprio(1);                                               \
    _Pragma("unroll") for (int _m = 0; _m < 4; ++_m)                             \
    _Pragma("unroll") for (int _n = 0; _n < 2; ++_n) {                           \
        acc[(mb)+_m][(nb)+_n] = __builtin_amdgcn_mfma_f32_16x16x32_bf16(         \
            bF[_n][0], aR[_m][0], acc[(mb)+_m][(nb)+_n], 0, 0, 0);               \
        acc[(mb)+_m][(nb)+_n] = __builtin_amdgcn_mfma_f32_16x16x32_bf16(         \
            bF[_n][1], aR[_m][1], acc[(mb)+_m][(nb)+_n], 0, 0, 0); }             \
    __builtin_amdgcn_s_setprio(0);                                               \
    __builtin_amdgcn_sched_barrier(0);                                           \
} while (0)

#define BARF() do { __builtin_amdgcn_sched_barrier(0);                           \
    __builtin_amdgcn_s_barrier();                                                \
    __builtin_amdgcn_sched_barrier(0); } while (0)

__global__ __launch_bounds__(512, 2) void sru_gemm8(const ushort* __restrict__ A,
                                                    const ushort* __restrict__ Bt,
                                                    const float*  __restrict__ bias,
                                                    ushort* __restrict__ u0,
                                                    ushort* __restrict__ g1,
                                                    ushort* __restrict__ g2) {
    __shared__ alignas(16) ushort lds8[65536];   // 128 KiB

    // supertile swizzle: per XCD (192 blocks), 4bm x 4bn supertiles (FETCH 670->309 MB, r16)
    int bid = blockIdx.x;
    int xcd = bid & 7, local = bid >> 3;
    int st = local >> 4, wi = local & 15;
    int bm0 = (xcd * 8 + (st & 1) * 4 + (wi & 3)) * 256;
    int bn0 = ((st >> 1) * 4 + (wi >> 2)) * 256;

    int tid  = threadIdx.x;
    int wave = tid >> 6, lane = tid & 63;
    int wm = wave >> 2, wn = wave & 3;

    int idx    = tid >> 3;
    int schunk = (tid & 7) ^ (idx & 7);
    int akc    = schunk * 8;
    int brow0  = (idx >> 5) * 64 + (idx & 31);
    int brow1  = ((idx >> 5) + 2) * 64 + (idx & 31);
    const ushort* Ab = A  + (size_t)bm0 * DIN;
    const ushort* Bb = Bt + (size_t)bn0 * DIN;

    int lrow = lane & 15, lk = lane >> 4, lx = lane & 7;
    int cs0  = ((0 + lk) ^ lx) * 8;
    int cs1  = ((4 + lk) ^ lx) * 8;
    int a_rb = (wm * 64 + lrow) * 64;
    int b_rb = (wn * 32 + lrow) * 64;

    f32x4 acc[8][4];
    f32x4 zero = {0.f, 0.f, 0.f, 0.f};
#pragma unroll
    for (int i = 0; i < 8; ++i)
#pragma unroll
        for (int j = 0; j < 4; ++j) acc[i][j] = zero;

    // prologue: tile0 -> buf0 (8 instr), tile1 -> buf1 (8 instr); drain tile0; publish;
    // pre-read aFA,bF0 of tile0.
    STAGE_A(0, 0, 0); STAGE_A(0, 1, 0); STAGE_B(0, 0, 0); STAGE_B(0, 1, 0);
    STAGE_A(1, 0, 1); STAGE_A(1, 1, 1); STAGE_B(1, 0, 1); STAGE_B(1, 1, 1);
    asm volatile("s_waitcnt vmcnt(8)" ::: "memory");
    BARF();

    short8 aFA[4][2], aFB[4][2], bF0[2][2], bF1[2][2];
    LD_A2(aFA, 0, 0);
    LD_B(0, 0, bF0);
    __builtin_amdgcn_sched_barrier(0);

    for (int t = 0; t < NT; ++t) {
        int cur = t & 1, nxt = cur ^ 1;
        // P0: read aFB (first!) then bF1; MM(A0xB0), MM(A0xB1)
        LD_A2(aFB, cur, 1);
        LD_B(cur, 1, bF1);
        BARF();
        MM(0, aFA, bF0, 0);
        MM(0, aFA, bF1, 2);
        // P1: drain tile t+1; publish; stage tile t+2 (into cur); read next-tile
        // aFA; MM(A1xB0), MM(A1xB1); read next-tile bF0 (after MMs: reg clash)
        asm volatile("s_waitcnt vmcnt(0)" ::: "memory");
        BARF();
        STAGE_A(cur, 0, t + 2); STAGE_A(cur, 1, t + 2);
        STAGE_B(cur, 0, t + 2); STAGE_B(cur, 1, t + 2);
        LD_A2(aFA, nxt, 0);
        MM(4, aFB, bF0, 0);
        MM(4, aFB, bF1, 2);
        LD_B(nxt, 0, bF0);
        __builtin_amdgcn_sched_barrier(0);
    }
    asm volatile("s_waitcnt vmcnt(0)" ::: "memory");  // drain dead tail stages

    int region = bn0 >> 11;                      // 0:u0 1:g1 2:g2
    int colb = (bn0 & (DD - 1)) + wn * 64 + ((lane >> 4) << 2);
    int rowm = bm0 + wm * 128 + (lane & 15);
    if (region == 0) {
#pragma unroll
        for (int j = 0; j < 4; ++j)
#pragma unroll
            for (int i = 0; i < 4; ++i) {
                f32x4 v = acc[i][j];
                uint32_t lo, hi;
                asm("v_cvt_pk_bf16_f32 %0, %1, %2" : "=v"(lo) : "v"(v[0]), "v"(v[1]));
                asm("v_cvt_pk_bf16_f32 %0, %1, %2" : "=v"(hi) : "v"(v[2]), "v"(v[3]));
                uint2 pk; pk.x = lo; pk.y = hi;
                *(uint2*)&u0[(size_t)(rowm + i * 16) * DD + colb + j * 16] = pk;
                f32x4 w = acc[4 + i][j];
                asm("v_cvt_pk_bf16_f32 %0, %1, %2" : "=v"(lo) : "v"(w[0]), "v"(w[1]));
                asm("v_cvt_pk_bf16_f32 %0, %1, %2" : "=v"(hi) : "v"(w[2]), "v"(w[3]));
                pk.x = lo; pk.y = hi;
                *(uint2*)&u0[(size_t)(rowm + 64 + i * 16) * DD + colb + j * 16] = pk;
            }
    } else {
        const float* bp = bias + (size_t)(region - 1) * DD;
        ushort* gp = (region == 1) ? g1 : g2;
#pragma unroll
        for (int j = 0; j < 4; ++j) {
            float4 bv = *(const float4*)&bp[colb + j * 16];
#pragma unroll
            for (int i = 0; i < 8; ++i) {
                f32x4 v = acc[i][j];
                float s0 = 1.f / (1.f + __expf(-(v[0] + bv.x)));
                float s1 = 1.f / (1.f + __expf(-(v[1] + bv.y)));
                float s2 = 1.f / (1.f + __expf(-(v[2] + bv.z)));
                float s3 = 1.f / (1.f + __expf(-(v[3] + bv.w)));
                uint32_t lo, hi;
                asm("v_cvt_pk_bf16_f32 %0, %1, %2" : "=v"(lo) : "v"(s0), "v"(s1));
                asm("v_cvt_pk_bf16_f32 %0, %1, %2" : "=v"(hi) : "v"(s2), "v"(s3));
                uint2 pk; pk.x = lo; pk.y = hi;
                int rr = rowm + (i >> 2) * 64 + (i & 3) * 16;
                *(uint2*)&gp[(size_t)rr * DD + colb + j * 16] = pk;
            }
        }
    }
}

// ---------------- K2: recurrence — round-8 form, unroll 32 ------------------------------
__global__ __launch_bounds__(64) void sru_rec(const ushort* __restrict__ u0,
                                              const ushort* __restrict__ g1,
                                              const ushort* __restrict__ g2,
                                              const ushort* __restrict__ xb,
                                              const float*  __restrict__ c0,
                                              float* __restrict__ h,
                                              float* __restrict__ c_last) {
    int t = blockIdx.x * 64 + threadIdx.x;   // t = b*DD + d
    float c = c0[t];
#pragma unroll 32
    for (int l = 0; l < L_SEQ; ++l) {
        int ix = l * (BSZ * DD) + t;
        float uu  = bf2f(u0[ix]);
        float gg1 = bf2f(g1[ix]);
        float gg2 = bf2f(g2[ix]);
        float xx  = bf2f(xb[ix]);
        c = (c - uu) * gg1 + uu;
        float e  = __expf(-2.f * fabsf(c));
        float th = (1.f - e) / (1.f + e);
        th = copysignf(th, c);
        h[ix] = (th - xx) * gg2 + xx;
    }
    c_last[t] = c;
}

extern "C" void kernel_launch(void* const* d_in, const int* in_sizes, int n_in,
                              void* d_out, int out_size, void* d_ws, size_t ws_size,
                              hipStream_t stream) {
    const float* x    = (const float*)d_in[0];
    const float* c0   = (const float*)d_in[1];
    const float* W    = (const float*)d_in[2];
    const float* bias = (const float*)d_in[3];
    float* out = (float*)d_out;

    char* ws = (char*)d_ws;
    ushort* xb = (ushort*)(ws);                       //  67,108,864 B  (x bf16)
    ushort* WT = (ushort*)(ws + 67108864);            //  25,165,824 B  (W^T bf16, deinterleaved)
    ushort* u0 = (ushort*)(ws + 92274688);            //  67,108,864 B  (u0 bf16)
    ushort* g1 = (ushort*)(ws + 159383552);           //  67,108,864 B
    ushort* g2 = (ushort*)(ws + 226492416);           //  67,108,864 B  -> 293,601,280 total

    hipLaunchKernelGGL(pre_kernel, dim3(5120), dim3(256), 0, stream,
                       (const f32x4*)x, (ushort4v*)xb, W, WT);
    hipLaunchKernelGGL(sru_gemm8, dim3(1536), dim3(512), 0, stream, xb, WT, bias, u0, g1, g2);
    hipLaunchKernelGGL(sru_rec, dim3(512), dim3(64), 0, stream,
                       u0, g1, g2, xb, c0, out, out + (size_t)MROWS * DD);
}